// Round 9
// baseline (545.272 us; speedup 1.0000x reference)
//
#include <hip/hip_runtime.h>
#include <math.h>

// Problem constants
#define NB   4
#define NH   8
#define SEQ  1024
#define DM   512
#define HD   64
#define WANT 715      // 0-indexed rank of the 716th-largest (kk = int(1024*0.7) = 716)
#define ROWS 8        // query rows per attention block (ROWS=4 regressed: scratch round-trip, r7)

// ws layout (float offsets)
#define OFF_Q    0u        // (B,H,L,64)  q
#define OFF_KT   2097152u  // (B,H,64,L)  k transposed (fp32)
#define OFF_VT   4194304u  // (B,H,64,L)  v transposed (fp32)
#define OFF_AO   6291456u  // (B,L,512)   attention output (pre-proj)
#define OFF_PART 8388608u  // (B,8,512)   pooling partials
#define OFF_CMB  8404992u  // (B,4)       combined-mask values {c00,c10,c01,c11}
#define OFF_MSUM 8405008u  // (B,)        int mask row-sums
#define OFF_JIT  8405504u  // (2^25,)     precomputed jitter (optional, ws_size permitting)
#define WS_NEED_BYTES ((size_t)(OFF_JIT + 33554432u) * 4u)

// ---------------- jitter replication: jax.random.normal(key(42), ...) -----------

__device__ __forceinline__ unsigned rotl32(unsigned x, int r){ return (x<<r)|(x>>(32-r)); }

__device__ __forceinline__ uint2 threefry_0_42(unsigned x0, unsigned x1){
  const unsigned ks0=0u, ks1=42u, ks2=0x1BD11BDAu^42u;
  x0+=ks0; x1+=ks1;
#define TFR(r) { x0+=x1; x1=rotl32(x1,(r)); x1^=x0; }
  TFR(13) TFR(15) TFR(26) TFR(6)
  x0+=ks1; x1+=ks2+1u;
  TFR(17) TFR(29) TFR(16) TFR(24)
  x0+=ks2; x1+=ks0+2u;
  TFR(13) TFR(15) TFR(26) TFR(6)
  x0+=ks0; x1+=ks1+3u;
  TFR(17) TFR(29) TFR(16) TFR(24)
  x0+=ks1; x1+=ks2+4u;
  TFR(13) TFR(15) TFR(26) TFR(6)
  x0+=ks2; x1+=ks0+5u;
#undef TFR
  return make_uint2(x0,x1);
}

// XLA ErfInv32 (Giles) — fast-log variant (jitter tolerates ~1e-3 rel error;
// top-k order only flips for s-gaps < ~1e-9, essentially never)
__device__ __forceinline__ float erfinv_xla(float x){
  float w = -__logf(fmaf(-x, x, 1.0f));
  float p;
  if (w < 5.0f) {
    w -= 2.5f;
    p = 2.81022636e-08f;
    p = fmaf(p,w, 3.43273939e-07f);
    p = fmaf(p,w,-3.5233877e-06f);
    p = fmaf(p,w,-4.39150654e-06f);
    p = fmaf(p,w, 0.00021858087f);
    p = fmaf(p,w,-0.00125372503f);
    p = fmaf(p,w,-0.00417768164f);
    p = fmaf(p,w, 0.246640727f);
    p = fmaf(p,w, 1.50140941f);
  } else {
    w = sqrtf(w) - 3.0f;
    p = -0.000200214257f;
    p = fmaf(p,w, 0.000100950558f);
    p = fmaf(p,w, 0.00134934322f);
    p = fmaf(p,w,-0.00367342844f);
    p = fmaf(p,w, 0.00573950773f);
    p = fmaf(p,w,-0.0076224613f);
    p = fmaf(p,w, 0.00943887047f);
    p = fmaf(p,w, 1.00167406f);
    p = fmaf(p,w, 2.83297682f);
  }
  return p*x;
}

__device__ __forceinline__ float norm_from_bits(unsigned bits){
  float fl = __uint_as_float((bits >> 9) | 0x3F800000u) - 1.0f; // [0,1)
  float u  = fmaf(fl, 2.0f, -0.99999994f);
  u = fmaxf(-0.99999994f, u);
  return (1.41421356f * erfinv_xla(u)) * 1e-6f;
}

// jitter element at flat index f of the (4,8,1024,1024) normal draw, times 1e-6.
__device__ __forceinline__ float jitter_val(unsigned f){
  unsigned i   = f & 0xFFFFFFu;
  unsigned sel = f >> 24;
  uint2 rr = threefry_0_42(i, i + 0x1000000u);
  return norm_from_bits(sel ? rr.y : rr.x);
}

// ---------------- K-1: jitter precompute (one threefry -> two outputs) ----------------
__global__ __launch_bounds__(256) void k_jit(float* __restrict__ jit){
  unsigned i = blockIdx.x*256u + threadIdx.x;
  uint2 rr = threefry_0_42(i, i + 0x1000000u);
  jit[i]              = norm_from_bits(rr.x);
  jit[i + 0x1000000u] = norm_from_bits(rr.y);
}

// ---------------- K0: pooling partials ----------------
__global__ __launch_bounds__(512) void k_pool(const float* __restrict__ x, float* __restrict__ part) {
  int b = blockIdx.x, ch = blockIdx.y, c = threadIdx.x;
  const float* xp = x + ((size_t)(b*SEQ + ch*128))*DM + c;
  float s = 0.f;
  for (int l=0;l<128;l++) s += xp[(size_t)l*DM];
  part[(b*8+ch)*DM + c] = s;
}

// ---------------- K1: pattern-selector MLP -> combined-mask values ----------------
__global__ __launch_bounds__(512) void k_pattern(const float* __restrict__ part, const int* __restrict__ mask,
    const float* __restrict__ w1, const float* __restrict__ b1,
    const float* __restrict__ w2, const float* __restrict__ b2,
    const float* __restrict__ w3, const float* __restrict__ b3,
    const float* __restrict__ pbias, float* __restrict__ cmb, int* __restrict__ msum) {
  __shared__ __align__(16) float pooled[DM];
  __shared__ __align__(16) float h1[DM];
  __shared__ __align__(16) float h2[DM/2];
  __shared__ float lg[3];
  __shared__ int msum_s;
  int b = blockIdx.x, t = threadIdx.x;
  float p = 0.f;
  for (int ch=0; ch<8; ++ch) p += part[(b*8+ch)*DM + t];
  pooled[t] = p * (1.0f/1024.0f);
  if (t == 0) msum_s = 0;
  __syncthreads();
  atomicAdd(&msum_s, mask[b*SEQ + t] + mask[b*SEQ + 512 + t]);
  // h1 = relu(pooled @ w1.T + b1)  (float4 loads, scalar ascending adds -> bit-identical)
  {
    float a = 0.f; const float4* wr = (const float4*)(w1 + (size_t)t*DM);
    const float4* pp = (const float4*)pooled;
    for (int c4=0;c4<DM/4;c4++) {
      float4 wv4 = wr[c4], pv4 = pp[c4];
      a += wv4.x*pv4.x; a += wv4.y*pv4.y; a += wv4.z*pv4.z; a += wv4.w*pv4.w;
    }
    a += b1[t];
    h1[t] = fmaxf(a, 0.f);
  }
  __syncthreads();
  if (t < 256) {
    float a = 0.f; const float4* wr = (const float4*)(w2 + (size_t)t*DM);
    const float4* hh = (const float4*)h1;
    for (int c4=0;c4<DM/4;c4++) {
      float4 wv4 = wr[c4], hv4 = hh[c4];
      a += wv4.x*hv4.x; a += wv4.y*hv4.y; a += wv4.z*hv4.z; a += wv4.w*hv4.w;
    }
    a += b2[t];
    h2[t] = fmaxf(a, 0.f);
  }
  __syncthreads();
  if (t < 3) {
    float a = 0.f; const float4* wr = (const float4*)(w3 + t*256);
    const float4* hh = (const float4*)h2;
    for (int c4=0;c4<64;c4++) {
      float4 wv4 = wr[c4], hv4 = hh[c4];
      a += wv4.x*hv4.x; a += wv4.y*hv4.y; a += wv4.z*hv4.z; a += wv4.w*hv4.w;
    }
    a += b3[t] + pbias[t];
    lg[t] = a * 2.0f;      // /PTEMP (0.5)
  }
  __syncthreads();
  if (t == 0) {
    float m = fmaxf(lg[0], fmaxf(lg[1], lg[2]));
    float e0 = expf(lg[0]-m), e1 = expf(lg[1]-m), e2 = expf(lg[2]-m);
    float Z = e0+e1+e2;
    float pw0 = e0/Z, pw1 = e1/Z, pw2 = e2/Z;
    cmb[b*4+0] = pw1;
    cmb[b*4+1] = pw0 + pw1;
    cmb[b*4+2] = pw1 + pw2;
    cmb[b*4+3] = (pw0 + pw1) + pw2;
    msum[b] = msum_s;
  }
}

// ---------------- K2: QKV projection (fp32 tiled GEMM, 128x64 tile, routed stores) ----------------
// 128-row M-tile: 8+4 LDS reads feed 32 FMA. Per-output accumulation stays
// single-acc ascending-k -> bit-identical q/k/v. (validated r7)
__global__ __launch_bounds__(256) void k_qkv(const float* __restrict__ x, const float* __restrict__ w,
                                             float* __restrict__ ws) {
  __shared__ __align__(16) float As[32][128];   // 16KB
  __shared__ __align__(16) float Bs[32][64];    // 8KB
  int tid = threadIdx.x;
  int bm = blockIdx.x, bn = blockIdx.y;
  int ty = tid >> 4, tx = tid & 15;
  float acc[8][4] = {};
  for (int kt=0; kt<16; ++kt) {
    #pragma unroll
    for (int q4=0;q4<4;q4++) {
      int f = tid*4+q4; int row = f>>3; int cc = (f&7)*4;   // row 0..127
      float4 ga = *(const float4*)&x[(size_t)(bm*128+row)*DM + kt*32 + cc];
      As[cc+0][row]=ga.x; As[cc+1][row]=ga.y; As[cc+2][row]=ga.z; As[cc+3][row]=ga.w;
    }
    #pragma unroll
    for (int q4=0;q4<2;q4++) {
      int f = tid*2+q4; int row = f>>3; int cc = (f&7)*4;   // row 0..63
      float4 gb = *(const float4*)&w[(size_t)(bn*64+row)*DM + kt*32 + cc];
      Bs[cc+0][row]=gb.x; Bs[cc+1][row]=gb.y; Bs[cc+2][row]=gb.z; Bs[cc+3][row]=gb.w;
    }
    __syncthreads();
    #pragma unroll
    for (int kk=0;kk<32;kk++) {
      float4 a0 = *(const float4*)&As[kk][ty*8];
      float4 a1 = *(const float4*)&As[kk][ty*8+4];
      float4 b4 = *(const float4*)&Bs[kk][tx*4];
      float av[8] = {a0.x,a0.y,a0.z,a0.w,a1.x,a1.y,a1.z,a1.w};
      float bv[4] = {b4.x,b4.y,b4.z,b4.w};
      #pragma unroll
      for (int i=0;i<8;i++)
        #pragma unroll
        for (int j=0;j<4;j++)
          acc[i][j] += av[i]*bv[j];
    }
    __syncthreads();
  }
  int m0 = bn*64;
  int s = m0 >> 9;
  int h = (m0 >> 6) & 7;
  int b = bm >> 3;               // 8 blocks of 128 tokens per batch
  int l0 = (bm & 7) * 128;
  int d0 = tx*4;
  if (s == 0) {
    #pragma unroll
    for (int i=0;i<8;i++) {
      int l = l0 + ty*8 + i;
      float4 o = {acc[i][0],acc[i][1],acc[i][2],acc[i][3]};
      *(float4*)&ws[OFF_Q + ((size_t)((b*NH+h)*SEQ + l))*HD + d0] = o;
    }
  } else {
    unsigned off = (s == 1) ? OFF_KT : OFF_VT;
    size_t base = off + ((size_t)((b*NH+h)*HD))*SEQ;
    #pragma unroll
    for (int j=0;j<4;j++) {
      float4 c0 = {acc[0][j], acc[1][j], acc[2][j], acc[3][j]};
      float4 c1 = {acc[4][j], acc[5][j], acc[6][j], acc[7][j]};
      size_t cb = base + (size_t)(d0+j)*SEQ + l0 + ty*8;
      *(float4*)&ws[cb]     = c0;
      *(float4*)&ws[cb + 4] = c1;
    }
  }
}

// ---------------- K3: fused scores + jitter + top-k select + softmax + PV ----------------
// r9: pbuf halved to [4][SEQ] (16KB); P4 keeps p in registers, P5 stages rows in 2
// batches of 4 (write 4 rows -> PV those rows -> next 4). Every accumulation sequence
// (per-wave ascending keys, w0+w1+w2+w3 combine) unchanged -> bit-identical.
// LDS ~18.9KB -> 8 blocks/CU. V loaded twice (L2-hot). Register structure untouched
// (r7 lesson: ROWS/score/u shapes are codegen-fragile).
template<int USEJIT>
__global__ __launch_bounds__(256, 4) void k_attn(
    const float* __restrict__ ws_q, const float* __restrict__ ws_kT, const float* __restrict__ ws_vT,
    const int* __restrict__ mask, const float* __restrict__ cmb, const int* __restrict__ msum,
    const float* __restrict__ sparse_w, const float* __restrict__ sparse_b,
    const float* __restrict__ jit, float* __restrict__ ao) {
  __shared__ __align__(16) float pbuf[4][SEQ];         // 16KB; aliased: hist (8KB, P3), red (6KB, P5 tail)
  __shared__ __align__(16) float q_s[ROWS][HD];        // 2KB
  __shared__ float mxred[4][ROWS], smred[4][ROWS];
  __shared__ unsigned pfx_s[ROWS];
  __shared__ int want_s[ROWS];
  __shared__ float mxrow[ROWS], rowsum[ROWS];
  __shared__ float cmb_s[4];

  unsigned* hist = (unsigned*)&pbuf[0][0];             // [ROWS*256] = 8KB (P3 only)
  float (*red)[ROWS][HD] = (float (*)[ROWS][HD])&pbuf[0][0]; // [3][ROWS][HD] = 6KB (P5 tail only)

  int tid = threadIdx.x;
  int gid = blockIdx.x;
  int bh = gid >> 7;            // 0..31
  int rt = gid & 127;
  int b = bh >> 3, h = bh & 7;
  int qbase = rt * ROWS;

  // P0: stage q rows + combined values + init select state
  {
    const float* qp = ws_q + ((size_t)bh*SEQ + qbase)*HD;
    if (tid < 128) ((float4*)q_s)[tid] = ((const float4*)qp)[tid];
    if (tid < 4) cmb_s[tid] = cmb[b*4+tid];
    if (tid < ROWS) { pfx_s[tid] = 0u; want_s[tid] = WANT; }
  }
  __syncthreads();

  // P1: scores -> registers. score[c][r] for key j=tid*4+c, row r.
  float score[4][ROWS];
  {
    const float* kT = ws_kT + (size_t)bh*HD*SEQ;
    #pragma unroll
    for (int c=0;c<4;c++)
      #pragma unroll
      for (int r=0;r<ROWS;r++) score[c][r]=0.f;
    for (int d4=0; d4<16; ++d4) {
      float4 qv[ROWS];
      #pragma unroll
      for (int r=0;r<ROWS;r++) qv[r] = *(const float4*)&q_s[r][d4*4];
      float4 ka = *(const float4*)&kT[(size_t)(d4*4+0)*SEQ + tid*4];
      float4 kb = *(const float4*)&kT[(size_t)(d4*4+1)*SEQ + tid*4];
      float4 kc = *(const float4*)&kT[(size_t)(d4*4+2)*SEQ + tid*4];
      float4 kd = *(const float4*)&kT[(size_t)(d4*4+3)*SEQ + tid*4];
      #pragma unroll
      for (int r=0;r<ROWS;r++) {
        score[0][r] += qv[r].x*ka.x + qv[r].y*kb.x + qv[r].z*kc.x + qv[r].w*kd.x;
        score[1][r] += qv[r].x*ka.y + qv[r].y*kb.y + qv[r].z*kc.y + qv[r].w*kd.y;
        score[2][r] += qv[r].x*ka.z + qv[r].y*kb.z + qv[r].z*kc.z + qv[r].w*kd.z;
        score[3][r] += qv[r].x*ka.w + qv[r].y*kb.w + qv[r].z*kc.w + qv[r].w*kd.w;
      }
    }
    #pragma unroll
    for (int c=0;c<4;c++)
      #pragma unroll
      for (int r=0;r<ROWS;r++)
        score[c][r] *= 0.125f;   // * hd^-0.5
  }

  // P2: sortable(s + jitter) -> registers
  unsigned u[4][ROWS];
  {
    float sw = sparse_w[h], sb = sparse_b[h];
    #pragma unroll
    for (int r=0;r<ROWS;r++) {
      unsigned fbase = ((unsigned)bh << 20) + ((unsigned)(qbase + r) << 10);
      float jv[4];
      if (USEJIT) {
        float4 j4 = *(const float4*)&jit[fbase + (unsigned)(tid*4)];
        jv[0]=j4.x; jv[1]=j4.y; jv[2]=j4.z; jv[3]=j4.w;
      } else {
        #pragma unroll
        for (int c=0;c<4;c++) jv[c] = jitter_val(fbase + (unsigned)(tid*4+c));
      }
      #pragma unroll
      for (int c=0;c<4;c++) {
        float s = score[c][r]*sw + sb + jv[c];
        unsigned bu = __float_as_uint(s);
        u[c][r] = (bu & 0x80000000u) ? ~bu : (bu | 0x80000000u);
      }
    }
  }

  // P3: exact 716th-largest per row via 4-pass radix select (values from registers).
  // Pass 0 dedups the all-equal-digit case (counts identical, fewer same-addr atomics).
  {
    int r2 = tid >> 5, w = tid & 31;    // 32 threads scan per row
    for (int pass=0; pass<4; ++pass) {
      int shift = 24 - 8*pass;
      for (int e = tid; e < ROWS*256; e += 256) hist[e] = 0u;
      __syncthreads();
      if (pass == 0) {
        #pragma unroll
        for (int r=0;r<ROWS;r++) {
          unsigned a = u[0][r] >> 24, bb = u[1][r] >> 24,
                   cc = u[2][r] >> 24, dd = u[3][r] >> 24;
          if (a == bb && a == cc && a == dd) {
            atomicAdd(&hist[r*256 + a], 4u);
          } else {
            atomicAdd(&hist[r*256 + a], 1u);
            atomicAdd(&hist[r*256 + bb], 1u);
            atomicAdd(&hist[r*256 + cc], 1u);
            atomicAdd(&hist[r*256 + dd], 1u);
          }
        }
      } else {
        unsigned hmask = 0xFFFFFFFFu << (shift+8);
        #pragma unroll
        for (int r=0;r<ROWS;r++) {
          unsigned pf = pfx_s[r];
          #pragma unroll
          for (int c=0;c<4;c++) {
            unsigned uu = u[c][r];
            if ((uu & hmask) == pf) atomicAdd(&hist[r*256 + ((uu>>shift)&255u)], 1u);
          }
        }
      }
      __syncthreads();
      unsigned cs = 0;
      #pragma unroll
      for (int k=0;k<8;k++) cs += hist[r2*256 + w*8 + k];
      unsigned is = cs;
      #pragma unroll
      for (int off=1; off<32; off<<=1) {
        unsigned tt = __shfl_down(is, off, 32);
        if (w + off < 32) is += tt;
      }
      unsigned es = is - cs;   // count in strictly-higher chunks
      int want = want_s[r2];
      if ((int)es <= want && want < (int)(es + cs)) {
        int cacc = (int)es;
        for (int k=7;k>=0;k--) {
          unsigned hc = hist[r2*256 + w*8 + k];
          if (want < cacc + (int)hc) {
            pfx_s[r2] |= ((unsigned)(w*8+k)) << shift;
            want_s[r2] = want - cacc;
            break;
          }
          cacc += (int)hc;
        }
      }
      __syncthreads();
    }
  }

  // pack sparse-select bits, freeing u[]
  unsigned spmask = 0u;
  {
    #pragma unroll
    for (int r=0;r<ROWS;r++) {
      unsigned Tr = pfx_s[r];
      #pragma unroll
      for (int c=0;c<4;c++)
        if (u[c][r] >= Tr) spmask |= 1u << (r*4+c);
    }
  }

  // P4: masking + block-wide softmax; p stays in score[] registers (no pbuf write here)
  {
    float c00 = cmb_s[0], c10 = cmb_s[1], c01 = cmb_s[2], c11 = cmb_s[3];
    int msum_b = msum[b];
    const int4 m4 = *(const int4*)&mask[b*SEQ + tid*4];
    int mv[4] = {m4.x, m4.y, m4.z, m4.w};
    bool okm[4];
    #pragma unroll
    for (int c=0;c<4;c++) {
      int j = tid*4 + c;
      okm[c] = (mv[c] != 0) || (msum_b == 0 && j == 0);
    }
    float lmax[ROWS];
    #pragma unroll
    for (int r=0;r<ROWS;r++) {
      int qr = qbase + r;
      float lm = -INFINITY;
      #pragma unroll
      for (int c=0;c<4;c++) {
        int j = tid*4 + c;
        bool sp = (spmask >> (r*4+c)) & 1u;
        int dj = j - qr; dj = dj < 0 ? -dj : dj;
        float comb = (dj <= 16) ? (sp ? c11 : c10) : (sp ? c01 : c00);
        float val = (comb > 0.1f && okm[c]) ? score[c][r] : -INFINITY;
        score[c][r] = val;
        lm = fmaxf(lm, val);
      }
      lmax[r] = lm;
    }
    #pragma unroll
    for (int r=0;r<ROWS;r++)
      #pragma unroll
      for (int off=32; off>=1; off>>=1)
        lmax[r] = fmaxf(lmax[r], __shfl_xor(lmax[r], off, 64));
    int wv = tid >> 6, lane = tid & 63;
    if (lane == 0) {
      #pragma unroll
      for (int r=0;r<ROWS;r++) mxred[wv][r] = lmax[r];
    }
    __syncthreads();
    if (tid < ROWS)
      mxrow[tid] = fmaxf(fmaxf(mxred[0][tid], mxred[1][tid]), fmaxf(mxred[2][tid], mxred[3][tid]));
    __syncthreads();
    float lsum[ROWS];
    #pragma unroll
    for (int r=0;r<ROWS;r++) {
      float M = mxrow[r];
      bool allm = (M == -INFINITY);
      float p0, p1, p2, p3;
      if (allm) {
        p0 = (tid == 0) ? 1.0f : 0.0f; p1 = 0.f; p2 = 0.f; p3 = 0.f;
      } else {
        p0 = __expf(score[0][r] - M);
        p1 = __expf(score[1][r] - M);
        p2 = __expf(score[2][r] - M);
        p3 = __expf(score[3][r] - M);
      }
      score[0][r] = p0; score[1][r] = p1; score[2][r] = p2; score[3][r] = p3;
      lsum[r] = p0+p1+p2+p3;
    }
    #pragma unroll
    for (int r=0;r<ROWS;r++)
      #pragma unroll
      for (int off=32; off>=1; off>>=1)
        lsum[r] += __shfl_xor(lsum[r], off, 64);
    if (lane == 0) {
      #pragma unroll
      for (int r=0;r<ROWS;r++) smred[wv][r] = lsum[r];
    }
    __syncthreads();
    if (tid < ROWS)
      rowsum[tid] = smred[0][tid] + smred[1][tid] + smred[2][tid] + smred[3][tid];
  }

  // P5: PV in 2 row-batches through the halved pbuf. Wave wv owns keys
  // [wv*256, wv*256+256) ascending for every row; batching rows does not
  // change any accumulation order. V loads repeat per batch (L2-hot).
  {
    int wv = tid >> 6, l = tid & 63;
    const float* vt = ws_vT + ((size_t)bh*HD + l)*SEQ;
    float acc[ROWS];
    #pragma unroll
    for (int r=0;r<ROWS;r++) acc[r]=0.f;
    #pragma unroll
    for (int half=0; half<2; ++half) {
      __syncthreads();   // prev batch reads done (and hist alias, rowsum visibility)
      #pragma unroll
      for (int rr=0;rr<4;rr++) {
        int r = half*4 + rr;
        float4 pv = {score[0][r], score[1][r], score[2][r], score[3][r]};
        *(float4*)&pbuf[rr][tid*4] = pv;
      }
      __syncthreads();
      int jb = wv*256;
      for (int j8=0;j8<32;j8++) {
        int j = jb + j8*8;
        float4 va = *(const float4*)&vt[j];
        float4 vb = *(const float4*)&vt[j+4];
        #pragma unroll
        for (int rr=0;rr<4;rr++) {
          int r = half*4 + rr;
          float4 pa = *(const float4*)&pbuf[rr][j];
          float4 pb = *(const float4*)&pbuf[rr][j+4];
          acc[r] += pa.x*va.x + pa.y*va.y + pa.z*va.z + pa.w*va.w;
          acc[r] += pb.x*vb.x + pb.y*vb.y + pb.z*vb.z + pb.w*vb.w;
        }
      }
    }
    __syncthreads();   // all pbuf reads done before red (aliased) writes
    if (wv > 0) {
      #pragma unroll
      for (int r=0;r<ROWS;r++) red[wv-1][r][l] = acc[r];
    }
    __syncthreads();
    if (wv == 0) {
      #pragma unroll
      for (int r=0;r<ROWS;r++) {
        float tot = acc[r] + red[0][r][l] + red[1][r][l] + red[2][r][l];
        ao[((size_t)(b*SEQ + qbase + r))*DM + h*HD + l] = tot / rowsum[r];
      }
    }
  }
}

// ---------------- K4: output projection + bias (128x64 tile) ----------------
__global__ __launch_bounds__(256) void k_proj(const float* __restrict__ aoin, const float* __restrict__ w,
                                              const float* __restrict__ bias, float* __restrict__ out) {
  __shared__ __align__(16) float As[32][128];   // 16KB
  __shared__ __align__(16) float Bs[32][64];    // 8KB
  int tid = threadIdx.x;
  int bm = blockIdx.x, bn = blockIdx.y;
  int ty = tid >> 4, tx = tid & 15;
  float acc[8][4] = {};
  for (int kt=0; kt<16; ++kt) {
    #pragma unroll
    for (int q4=0;q4<4;q4++) {
      int f = tid*4+q4; int row = f>>3; int cc = (f&7)*4;   // row 0..127
      float4 ga = *(const float4*)&aoin[(size_t)(bm*128+row)*DM + kt*32 + cc];
      As[cc+0][row]=ga.x; As[cc+1][row]=ga.y; As[cc+2][row]=ga.z; As[cc+3][row]=ga.w;
    }
    #pragma unroll
    for (int q4=0;q4<2;q4++) {
      int f = tid*2+q4; int row = f>>3; int cc = (f&7)*4;   // row 0..63
      float4 gb = *(const float4*)&w[(size_t)(bn*64+row)*DM + kt*32 + cc];
      Bs[cc+0][row]=gb.x; Bs[cc+1][row]=gb.y; Bs[cc+2][row]=gb.z; Bs[cc+3][row]=gb.w;
    }
    __syncthreads();
    #pragma unroll
    for (int kk=0;kk<32;kk++) {
      float4 a0 = *(const float4*)&As[kk][ty*8];
      float4 a1 = *(const float4*)&As[kk][ty*8+4];
      float4 b4 = *(const float4*)&Bs[kk][tx*4];
      float av[8] = {a0.x,a0.y,a0.z,a0.w,a1.x,a1.y,a1.z,a1.w};
      float bv[4] = {b4.x,b4.y,b4.z,b4.w};
      #pragma unroll
      for (int i=0;i<8;i++)
        #pragma unroll
        for (int j=0;j<4;j++)
          acc[i][j] += av[i]*bv[j];
    }
    __syncthreads();
  }
  int o0 = bn*64 + tx*4;
  float4 bvv = *(const float4*)&bias[o0];
  #pragma unroll
  for (int i=0;i<8;i++) {
    int tok = bm*128 + ty*8 + i;
    float4 o;
    o.x = acc[i][0] + bvv.x; o.y = acc[i][1] + bvv.y;
    o.z = acc[i][2] + bvv.z; o.w = acc[i][3] + bvv.w;
    *(float4*)&out[(size_t)tok*DM + o0] = o;
  }
}

// ---------------- launch ----------------
extern "C" void kernel_launch(void* const* d_in, const int* in_sizes, int n_in,
                              void* d_out, int out_size, void* d_ws, size_t ws_size,
                              hipStream_t stream) {
  const float* x        = (const float*)d_in[0];
  const int*   mask     = (const int*)  d_in[1];
  const float* qkv_w    = (const float*)d_in[2];
  const float* proj_w   = (const float*)d_in[3];
  const float* proj_b   = (const float*)d_in[4];
  const float* ps_w1    = (const float*)d_in[5];
  const float* ps_b1    = (const float*)d_in[6];
  const float* ps_w2    = (const float*)d_in[7];
  const float* ps_b2    = (const float*)d_in[8];
  const float* ps_w3    = (const float*)d_in[9];
  const float* ps_b3    = (const float*)d_in[10];
  const float* pbias    = (const float*)d_in[11];
  const float* sparse_w = (const float*)d_in[12];
  const float* sparse_b = (const float*)d_in[13];
  float* ws  = (float*)d_ws;
  float* out = (float*)d_out;

  const bool use_jit = (ws_size >= WS_NEED_BYTES);

  k_pool<<<dim3(NB,8), 512, 0, stream>>>(x, ws + OFF_PART);
  k_pattern<<<NB, 512, 0, stream>>>(ws + OFF_PART, mask, ps_w1, ps_b1, ps_w2, ps_b2,
                                    ps_w3, ps_b3, pbias, ws + OFF_CMB, (int*)(ws + OFF_MSUM));
  if (use_jit) k_jit<<<65536, 256, 0, stream>>>(ws + OFF_JIT);
  k_qkv<<<dim3(32,24), 256, 0, stream>>>(x, qkv_w, ws);
  if (use_jit) {
    k_attn<1><<<NB*NH*(SEQ/ROWS), 256, 0, stream>>>(ws + OFF_Q, ws + OFF_KT, ws + OFF_VT, mask,
                                                    ws + OFF_CMB, (const int*)(ws + OFF_MSUM),
                                                    sparse_w, sparse_b, ws + OFF_JIT, ws + OFF_AO);
  } else {
    k_attn<0><<<NB*NH*(SEQ/ROWS), 256, 0, stream>>>(ws + OFF_Q, ws + OFF_KT, ws + OFF_VT, mask,
                                                    ws + OFF_CMB, (const int*)(ws + OFF_MSUM),
                                                    sparse_w, sparse_b, ws + OFF_JIT, ws + OFF_AO);
  }
  k_proj<<<dim3(32,8), 256, 0, stream>>>(ws + OFF_AO, proj_w, proj_b, out);
}

// Round 10
// 457.791 us; speedup vs baseline: 1.1911x; 1.1911x over previous
//
#include <hip/hip_runtime.h>
#include <math.h>

// Problem constants
#define NB   4
#define NH   8
#define SEQ  1024
#define DM   512
#define HD   64
#define WANT 715      // 0-indexed rank of the 716th-largest (kk = int(1024*0.7) = 716)
#define ROWS 8        // query rows per attention block (ROWS=4 regressed: scratch round-trip, r7)

typedef float v2f __attribute__((ext_vector_type(2)));
__device__ __forceinline__ v2f mkv2(float a, float b){ v2f r; r.x=a; r.y=b; return r; }

// ws layout (float offsets)
#define OFF_Q    0u        // (B,H,L,64)  q
#define OFF_KT   2097152u  // (B,H,64,L)  k transposed (fp32)
#define OFF_VT   4194304u  // (B,H,64,L)  v transposed (fp32)
#define OFF_AO   6291456u  // (B,L,512)   attention output (pre-proj)
#define OFF_PART 8388608u  // (B,8,512)   pooling partials
#define OFF_CMB  8404992u  // (B,4)       combined-mask values {c00,c10,c01,c11}
#define OFF_MSUM 8405008u  // (B,)        int mask row-sums
#define OFF_JIT  8405504u  // (2^25,)     precomputed jitter (optional, ws_size permitting)
#define WS_NEED_BYTES ((size_t)(OFF_JIT + 33554432u) * 4u)

// ---------------- jitter replication: jax.random.normal(key(42), ...) -----------

__device__ __forceinline__ unsigned rotl32(unsigned x, int r){ return (x<<r)|(x>>(32-r)); }

__device__ __forceinline__ uint2 threefry_0_42(unsigned x0, unsigned x1){
  const unsigned ks0=0u, ks1=42u, ks2=0x1BD11BDAu^42u;
  x0+=ks0; x1+=ks1;
#define TFR(r) { x0+=x1; x1=rotl32(x1,(r)); x1^=x0; }
  TFR(13) TFR(15) TFR(26) TFR(6)
  x0+=ks1; x1+=ks2+1u;
  TFR(17) TFR(29) TFR(16) TFR(24)
  x0+=ks2; x1+=ks0+2u;
  TFR(13) TFR(15) TFR(26) TFR(6)
  x0+=ks0; x1+=ks1+3u;
  TFR(17) TFR(29) TFR(16) TFR(24)
  x0+=ks1; x1+=ks2+4u;
  TFR(13) TFR(15) TFR(26) TFR(6)
  x0+=ks2; x1+=ks0+5u;
#undef TFR
  return make_uint2(x0,x1);
}

// XLA ErfInv32 (Giles) — fast-log variant (jitter tolerates ~1e-3 rel error;
// top-k order only flips for s-gaps < ~1e-9, essentially never)
__device__ __forceinline__ float erfinv_xla(float x){
  float w = -__logf(fmaf(-x, x, 1.0f));
  float p;
  if (w < 5.0f) {
    w -= 2.5f;
    p = 2.81022636e-08f;
    p = fmaf(p,w, 3.43273939e-07f);
    p = fmaf(p,w,-3.5233877e-06f);
    p = fmaf(p,w,-4.39150654e-06f);
    p = fmaf(p,w, 0.00021858087f);
    p = fmaf(p,w,-0.00125372503f);
    p = fmaf(p,w,-0.00417768164f);
    p = fmaf(p,w, 0.246640727f);
    p = fmaf(p,w, 1.50140941f);
  } else {
    w = sqrtf(w) - 3.0f;
    p = -0.000200214257f;
    p = fmaf(p,w, 0.000100950558f);
    p = fmaf(p,w, 0.00134934322f);
    p = fmaf(p,w,-0.00367342844f);
    p = fmaf(p,w, 0.00573950773f);
    p = fmaf(p,w,-0.0076224613f);
    p = fmaf(p,w, 0.00943887047f);
    p = fmaf(p,w, 1.00167406f);
    p = fmaf(p,w, 2.83297682f);
  }
  return p*x;
}

__device__ __forceinline__ float norm_from_bits(unsigned bits){
  float fl = __uint_as_float((bits >> 9) | 0x3F800000u) - 1.0f; // [0,1)
  float u  = fmaf(fl, 2.0f, -0.99999994f);
  u = fmaxf(-0.99999994f, u);
  return (1.41421356f * erfinv_xla(u)) * 1e-6f;
}

// jitter element at flat index f of the (4,8,1024,1024) normal draw, times 1e-6.
__device__ __forceinline__ float jitter_val(unsigned f){
  unsigned i   = f & 0xFFFFFFu;
  unsigned sel = f >> 24;
  uint2 rr = threefry_0_42(i, i + 0x1000000u);
  return norm_from_bits(sel ? rr.y : rr.x);
}

// ---------------- K-1: jitter precompute (one threefry -> two outputs) ----------------
__global__ __launch_bounds__(256) void k_jit(float* __restrict__ jit){
  unsigned i = blockIdx.x*256u + threadIdx.x;
  uint2 rr = threefry_0_42(i, i + 0x1000000u);
  jit[i]              = norm_from_bits(rr.x);
  jit[i + 0x1000000u] = norm_from_bits(rr.y);
}

// ---------------- K0: pooling partials ----------------
__global__ __launch_bounds__(512) void k_pool(const float* __restrict__ x, float* __restrict__ part) {
  int b = blockIdx.x, ch = blockIdx.y, c = threadIdx.x;
  const float* xp = x + ((size_t)(b*SEQ + ch*128))*DM + c;
  float s = 0.f;
  for (int l=0;l<128;l++) s += xp[(size_t)l*DM];
  part[(b*8+ch)*DM + c] = s;
}

// ---------------- K1: pattern-selector MLP -> combined-mask values ----------------
__global__ __launch_bounds__(512) void k_pattern(const float* __restrict__ part, const int* __restrict__ mask,
    const float* __restrict__ w1, const float* __restrict__ b1,
    const float* __restrict__ w2, const float* __restrict__ b2,
    const float* __restrict__ w3, const float* __restrict__ b3,
    const float* __restrict__ pbias, float* __restrict__ cmb, int* __restrict__ msum) {
  __shared__ __align__(16) float pooled[DM];
  __shared__ __align__(16) float h1[DM];
  __shared__ __align__(16) float h2[DM/2];
  __shared__ float lg[3];
  __shared__ int msum_s;
  int b = blockIdx.x, t = threadIdx.x;
  float p = 0.f;
  for (int ch=0; ch<8; ++ch) p += part[(b*8+ch)*DM + t];
  pooled[t] = p * (1.0f/1024.0f);
  if (t == 0) msum_s = 0;
  __syncthreads();
  atomicAdd(&msum_s, mask[b*SEQ + t] + mask[b*SEQ + 512 + t]);
  // h1 = relu(pooled @ w1.T + b1)  (float4 loads, scalar ascending adds -> bit-identical)
  {
    float a = 0.f; const float4* wr = (const float4*)(w1 + (size_t)t*DM);
    const float4* pp = (const float4*)pooled;
    for (int c4=0;c4<DM/4;c4++) {
      float4 wv4 = wr[c4], pv4 = pp[c4];
      a += wv4.x*pv4.x; a += wv4.y*pv4.y; a += wv4.z*pv4.z; a += wv4.w*pv4.w;
    }
    a += b1[t];
    h1[t] = fmaxf(a, 0.f);
  }
  __syncthreads();
  if (t < 256) {
    float a = 0.f; const float4* wr = (const float4*)(w2 + (size_t)t*DM);
    const float4* hh = (const float4*)h1;
    for (int c4=0;c4<DM/4;c4++) {
      float4 wv4 = wr[c4], hv4 = hh[c4];
      a += wv4.x*hv4.x; a += wv4.y*hv4.y; a += wv4.z*hv4.z; a += wv4.w*hv4.w;
    }
    a += b2[t];
    h2[t] = fmaxf(a, 0.f);
  }
  __syncthreads();
  if (t < 3) {
    float a = 0.f; const float4* wr = (const float4*)(w3 + t*256);
    const float4* hh = (const float4*)h2;
    for (int c4=0;c4<64;c4++) {
      float4 wv4 = wr[c4], hv4 = hh[c4];
      a += wv4.x*hv4.x; a += wv4.y*hv4.y; a += wv4.z*hv4.z; a += wv4.w*hv4.w;
    }
    a += b3[t] + pbias[t];
    lg[t] = a * 2.0f;      // /PTEMP (0.5)
  }
  __syncthreads();
  if (t == 0) {
    float m = fmaxf(lg[0], fmaxf(lg[1], lg[2]));
    float e0 = expf(lg[0]-m), e1 = expf(lg[1]-m), e2 = expf(lg[2]-m);
    float Z = e0+e1+e2;
    float pw0 = e0/Z, pw1 = e1/Z, pw2 = e2/Z;
    cmb[b*4+0] = pw1;
    cmb[b*4+1] = pw0 + pw1;
    cmb[b*4+2] = pw1 + pw2;
    cmb[b*4+3] = (pw0 + pw1) + pw2;
    msum[b] = msum_s;
  }
}

// ---------------- K2: QKV projection (fp32 tiled GEMM, 128x64 tile, packed FMA) ----------------
// Packed-pair accumulators: each v2f lane-half holds the SAME accumulator as the scalar
// version, receiving the SAME sequence of fused ops (__builtin_elementwise_fma ==
// v_fmac semantics) -> bit-identical q/k/v; 2x fewer FMA issues (v_pk_fma_f32).
__global__ __launch_bounds__(256) void k_qkv(const float* __restrict__ x, const float* __restrict__ w,
                                             float* __restrict__ ws) {
  __shared__ __align__(16) float As[32][128];   // 16KB
  __shared__ __align__(16) float Bs[32][64];    // 8KB
  int tid = threadIdx.x;
  int bm = blockIdx.x, bn = blockIdx.y;
  int ty = tid >> 4, tx = tid & 15;
  v2f acc2[8][2];
  #pragma unroll
  for (int i=0;i<8;i++) { acc2[i][0] = mkv2(0.f,0.f); acc2[i][1] = mkv2(0.f,0.f); }
  for (int kt=0; kt<16; ++kt) {
    #pragma unroll
    for (int q4=0;q4<4;q4++) {
      int f = tid*4+q4; int row = f>>3; int cc = (f&7)*4;   // row 0..127
      float4 ga = *(const float4*)&x[(size_t)(bm*128+row)*DM + kt*32 + cc];
      As[cc+0][row]=ga.x; As[cc+1][row]=ga.y; As[cc+2][row]=ga.z; As[cc+3][row]=ga.w;
    }
    #pragma unroll
    for (int q4=0;q4<2;q4++) {
      int f = tid*2+q4; int row = f>>3; int cc = (f&7)*4;   // row 0..63
      float4 gb = *(const float4*)&w[(size_t)(bn*64+row)*DM + kt*32 + cc];
      Bs[cc+0][row]=gb.x; Bs[cc+1][row]=gb.y; Bs[cc+2][row]=gb.z; Bs[cc+3][row]=gb.w;
    }
    __syncthreads();
    #pragma unroll
    for (int kk=0;kk<32;kk++) {
      float4 a0 = *(const float4*)&As[kk][ty*8];
      float4 a1 = *(const float4*)&As[kk][ty*8+4];
      float4 b4 = *(const float4*)&Bs[kk][tx*4];
      float av[8] = {a0.x,a0.y,a0.z,a0.w,a1.x,a1.y,a1.z,a1.w};
      v2f b01 = mkv2(b4.x,b4.y), b23 = mkv2(b4.z,b4.w);
      #pragma unroll
      for (int i=0;i<8;i++) {
        v2f s = mkv2(av[i], av[i]);
        acc2[i][0] = __builtin_elementwise_fma(s, b01, acc2[i][0]);
        acc2[i][1] = __builtin_elementwise_fma(s, b23, acc2[i][1]);
      }
    }
    __syncthreads();
  }
  float acc[8][4];
  #pragma unroll
  for (int i=0;i<8;i++) {
    acc[i][0]=acc2[i][0].x; acc[i][1]=acc2[i][0].y;
    acc[i][2]=acc2[i][1].x; acc[i][3]=acc2[i][1].y;
  }
  int m0 = bn*64;
  int s = m0 >> 9;
  int h = (m0 >> 6) & 7;
  int b = bm >> 3;               // 8 blocks of 128 tokens per batch
  int l0 = (bm & 7) * 128;
  int d0 = tx*4;
  if (s == 0) {
    #pragma unroll
    for (int i=0;i<8;i++) {
      int l = l0 + ty*8 + i;
      float4 o = {acc[i][0],acc[i][1],acc[i][2],acc[i][3]};
      *(float4*)&ws[OFF_Q + ((size_t)((b*NH+h)*SEQ + l))*HD + d0] = o;
    }
  } else {
    unsigned off = (s == 1) ? OFF_KT : OFF_VT;
    size_t base = off + ((size_t)((b*NH+h)*HD))*SEQ;
    #pragma unroll
    for (int j=0;j<4;j++) {
      float4 c0 = {acc[0][j], acc[1][j], acc[2][j], acc[3][j]};
      float4 c1 = {acc[4][j], acc[5][j], acc[6][j], acc[7][j]};
      size_t cb = base + (size_t)(d0+j)*SEQ + l0 + ty*8;
      *(float4*)&ws[cb]     = c0;
      *(float4*)&ws[cb + 4] = c1;
    }
  }
}

// ---------------- K3: fused scores + jitter + top-k select + softmax + PV ----------------
// EXACT round-8 structure for P0-P4 (score path untouched -> top-k flip set stable).
// P5 uses packed v2f accumulators (reorders only the PV summation, downstream of
// top-k/softmax -> ~1e-6 output drift max; 4096 -> 2048 FMA issues/thread).
template<int USEJIT>
__global__ __launch_bounds__(256, 4) void k_attn(
    const float* __restrict__ ws_q, const float* __restrict__ ws_kT, const float* __restrict__ ws_vT,
    const int* __restrict__ mask, const float* __restrict__ cmb, const int* __restrict__ msum,
    const float* __restrict__ sparse_w, const float* __restrict__ sparse_b,
    const float* __restrict__ jit, float* __restrict__ ao) {
  __shared__ __align__(16) float pbuf[ROWS][SEQ];      // 32KB; aliased: hist (8KB, P3), red (6KB, P5 tail)
  __shared__ __align__(16) float q_s[ROWS][HD];        // 2KB
  __shared__ float mxred[4][ROWS], smred[4][ROWS];
  __shared__ unsigned pfx_s[ROWS];
  __shared__ int want_s[ROWS];
  __shared__ float mxrow[ROWS], rowsum[ROWS];
  __shared__ float cmb_s[4];

  unsigned* hist = (unsigned*)&pbuf[0][0];             // [ROWS*256] = 8KB (P3 only)
  float (*red)[ROWS][HD] = (float (*)[ROWS][HD])&pbuf[0][0]; // [3][ROWS][HD] (P5 tail only)

  int tid = threadIdx.x;
  int gid = blockIdx.x;
  int bh = gid >> 7;            // 0..31
  int rt = gid & 127;
  int b = bh >> 3, h = bh & 7;
  int qbase = rt * ROWS;

  // P0: stage q rows + combined values + init select state
  {
    const float* qp = ws_q + ((size_t)bh*SEQ + qbase)*HD;
    if (tid < 128) ((float4*)q_s)[tid] = ((const float4*)qp)[tid];
    if (tid < 4) cmb_s[tid] = cmb[b*4+tid];
    if (tid < ROWS) { pfx_s[tid] = 0u; want_s[tid] = WANT; }
  }
  __syncthreads();

  // P1: scores -> registers. score[c][r] for key j=tid*4+c, row r.
  float score[4][ROWS];
  {
    const float* kT = ws_kT + (size_t)bh*HD*SEQ;
    #pragma unroll
    for (int c=0;c<4;c++)
      #pragma unroll
      for (int r=0;r<ROWS;r++) score[c][r]=0.f;
    for (int d4=0; d4<16; ++d4) {
      float4 qv[ROWS];
      #pragma unroll
      for (int r=0;r<ROWS;r++) qv[r] = *(const float4*)&q_s[r][d4*4];
      float4 ka = *(const float4*)&kT[(size_t)(d4*4+0)*SEQ + tid*4];
      float4 kb = *(const float4*)&kT[(size_t)(d4*4+1)*SEQ + tid*4];
      float4 kc = *(const float4*)&kT[(size_t)(d4*4+2)*SEQ + tid*4];
      float4 kd = *(const float4*)&kT[(size_t)(d4*4+3)*SEQ + tid*4];
      #pragma unroll
      for (int r=0;r<ROWS;r++) {
        score[0][r] += qv[r].x*ka.x + qv[r].y*kb.x + qv[r].z*kc.x + qv[r].w*kd.x;
        score[1][r] += qv[r].x*ka.y + qv[r].y*kb.y + qv[r].z*kc.y + qv[r].w*kd.y;
        score[2][r] += qv[r].x*ka.z + qv[r].y*kb.z + qv[r].z*kc.z + qv[r].w*kd.z;
        score[3][r] += qv[r].x*ka.w + qv[r].y*kb.w + qv[r].z*kc.w + qv[r].w*kd.w;
      }
    }
    #pragma unroll
    for (int c=0;c<4;c++)
      #pragma unroll
      for (int r=0;r<ROWS;r++)
        score[c][r] *= 0.125f;   // * hd^-0.5
  }

  // P2: sortable(s + jitter) -> registers
  unsigned u[4][ROWS];
  {
    float sw = sparse_w[h], sb = sparse_b[h];
    #pragma unroll
    for (int r=0;r<ROWS;r++) {
      unsigned fbase = ((unsigned)bh << 20) + ((unsigned)(qbase + r) << 10);
      float jv[4];
      if (USEJIT) {
        float4 j4 = *(const float4*)&jit[fbase + (unsigned)(tid*4)];
        jv[0]=j4.x; jv[1]=j4.y; jv[2]=j4.z; jv[3]=j4.w;
      } else {
        #pragma unroll
        for (int c=0;c<4;c++) jv[c] = jitter_val(fbase + (unsigned)(tid*4+c));
      }
      #pragma unroll
      for (int c=0;c<4;c++) {
        float s = score[c][r]*sw + sb + jv[c];
        unsigned bu = __float_as_uint(s);
        u[c][r] = (bu & 0x80000000u) ? ~bu : (bu | 0x80000000u);
      }
    }
  }

  // P3: exact 716th-largest per row via 4-pass radix select (values from registers).
  // Pass 0 dedups the all-equal-digit case (counts identical, fewer same-addr atomics).
  {
    int r2 = tid >> 5, w = tid & 31;    // 32 threads scan per row
    for (int pass=0; pass<4; ++pass) {
      int shift = 24 - 8*pass;
      for (int e = tid; e < ROWS*256; e += 256) hist[e] = 0u;
      __syncthreads();
      if (pass == 0) {
        #pragma unroll
        for (int r=0;r<ROWS;r++) {
          unsigned a = u[0][r] >> 24, bb = u[1][r] >> 24,
                   cc = u[2][r] >> 24, dd = u[3][r] >> 24;
          if (a == bb && a == cc && a == dd) {
            atomicAdd(&hist[r*256 + a], 4u);
          } else {
            atomicAdd(&hist[r*256 + a], 1u);
            atomicAdd(&hist[r*256 + bb], 1u);
            atomicAdd(&hist[r*256 + cc], 1u);
            atomicAdd(&hist[r*256 + dd], 1u);
          }
        }
      } else {
        unsigned hmask = 0xFFFFFFFFu << (shift+8);
        #pragma unroll
        for (int r=0;r<ROWS;r++) {
          unsigned pf = pfx_s[r];
          #pragma unroll
          for (int c=0;c<4;c++) {
            unsigned uu = u[c][r];
            if ((uu & hmask) == pf) atomicAdd(&hist[r*256 + ((uu>>shift)&255u)], 1u);
          }
        }
      }
      __syncthreads();
      unsigned cs = 0;
      #pragma unroll
      for (int k=0;k<8;k++) cs += hist[r2*256 + w*8 + k];
      unsigned is = cs;
      #pragma unroll
      for (int off=1; off<32; off<<=1) {
        unsigned tt = __shfl_down(is, off, 32);
        if (w + off < 32) is += tt;
      }
      unsigned es = is - cs;   // count in strictly-higher chunks
      int want = want_s[r2];
      if ((int)es <= want && want < (int)(es + cs)) {
        int cacc = (int)es;
        for (int k=7;k>=0;k--) {
          unsigned hc = hist[r2*256 + w*8 + k];
          if (want < cacc + (int)hc) {
            pfx_s[r2] |= ((unsigned)(w*8+k)) << shift;
            want_s[r2] = want - cacc;
            break;
          }
          cacc += (int)hc;
        }
      }
      __syncthreads();
    }
  }

  // pack sparse-select bits, freeing u[]
  unsigned spmask = 0u;
  {
    #pragma unroll
    for (int r=0;r<ROWS;r++) {
      unsigned Tr = pfx_s[r];
      #pragma unroll
      for (int c=0;c<4;c++)
        if (u[c][r] >= Tr) spmask |= 1u << (r*4+c);
    }
  }

  // P4: masking + block-wide softmax; p written to pbuf (float4 per row)
  {
    float c00 = cmb_s[0], c10 = cmb_s[1], c01 = cmb_s[2], c11 = cmb_s[3];
    int msum_b = msum[b];
    const int4 m4 = *(const int4*)&mask[b*SEQ + tid*4];
    int mv[4] = {m4.x, m4.y, m4.z, m4.w};
    bool okm[4];
    #pragma unroll
    for (int c=0;c<4;c++) {
      int j = tid*4 + c;
      okm[c] = (mv[c] != 0) || (msum_b == 0 && j == 0);
    }
    float lmax[ROWS];
    #pragma unroll
    for (int r=0;r<ROWS;r++) {
      int qr = qbase + r;
      float lm = -INFINITY;
      #pragma unroll
      for (int c=0;c<4;c++) {
        int j = tid*4 + c;
        bool sp = (spmask >> (r*4+c)) & 1u;
        int dj = j - qr; dj = dj < 0 ? -dj : dj;
        float comb = (dj <= 16) ? (sp ? c11 : c10) : (sp ? c01 : c00);
        float val = (comb > 0.1f && okm[c]) ? score[c][r] : -INFINITY;
        score[c][r] = val;
        lm = fmaxf(lm, val);
      }
      lmax[r] = lm;
    }
    #pragma unroll
    for (int r=0;r<ROWS;r++)
      #pragma unroll
      for (int off=32; off>=1; off>>=1)
        lmax[r] = fmaxf(lmax[r], __shfl_xor(lmax[r], off, 64));
    int wv = tid >> 6, lane = tid & 63;
    if (lane == 0) {
      #pragma unroll
      for (int r=0;r<ROWS;r++) mxred[wv][r] = lmax[r];
    }
    __syncthreads();
    if (tid < ROWS)
      mxrow[tid] = fmaxf(fmaxf(mxred[0][tid], mxred[1][tid]), fmaxf(mxred[2][tid], mxred[3][tid]));
    __syncthreads();
    float lsum[ROWS];
    #pragma unroll
    for (int r=0;r<ROWS;r++) {
      float M = mxrow[r];
      bool allm = (M == -INFINITY);
      float p0, p1, p2, p3;
      if (allm) {
        p0 = (tid == 0) ? 1.0f : 0.0f; p1 = 0.f; p2 = 0.f; p3 = 0.f;
      } else {
        p0 = __expf(score[0][r] - M);
        p1 = __expf(score[1][r] - M);
        p2 = __expf(score[2][r] - M);
        p3 = __expf(score[3][r] - M);
      }
      float4 pv = {p0,p1,p2,p3};
      *(float4*)&pbuf[r][tid*4] = pv;
      lsum[r] = p0+p1+p2+p3;
    }
    #pragma unroll
    for (int r=0;r<ROWS;r++)
      #pragma unroll
      for (int off=32; off>=1; off>>=1)
        lsum[r] += __shfl_xor(lsum[r], off, 64);
    if (lane == 0) {
      #pragma unroll
      for (int r=0;r<ROWS;r++) smred[wv][r] = lsum[r];
    }
    __syncthreads();
    if (tid < ROWS)
      rowsum[tid] = smred[0][tid] + smred[1][tid] + smred[2][tid] + smred[3][tid];
  }
  __syncthreads();

  // P5: PV with packed v2f accumulators. wave wv owns keys [wv*256, wv*256+256);
  // p reads are wave-uniform broadcasts. red aliases pbuf (written after all reads).
  {
    int wv = tid >> 6, l = tid & 63;
    const float* vt = ws_vT + ((size_t)bh*HD + l)*SEQ;
    v2f acc2[ROWS];
    #pragma unroll
    for (int r=0;r<ROWS;r++) acc2[r] = mkv2(0.f,0.f);
    int jb = wv*256;
    for (int j8=0;j8<32;j8++) {
      int j = jb + j8*8;
      float4 va = *(const float4*)&vt[j];
      float4 vb = *(const float4*)&vt[j+4];
      v2f va01 = mkv2(va.x,va.y), va23 = mkv2(va.z,va.w);
      v2f vb01 = mkv2(vb.x,vb.y), vb23 = mkv2(vb.z,vb.w);
      #pragma unroll
      for (int r=0;r<ROWS;r++) {
        float4 pa = *(const float4*)&pbuf[r][j];
        float4 pb = *(const float4*)&pbuf[r][j+4];
        v2f t = acc2[r];
        t = __builtin_elementwise_fma(mkv2(pa.x,pa.y), va01, t);
        t = __builtin_elementwise_fma(mkv2(pa.z,pa.w), va23, t);
        t = __builtin_elementwise_fma(mkv2(pb.x,pb.y), vb01, t);
        t = __builtin_elementwise_fma(mkv2(pb.z,pb.w), vb23, t);
        acc2[r] = t;
      }
    }
    float acc[ROWS];
    #pragma unroll
    for (int r=0;r<ROWS;r++) acc[r] = acc2[r].x + acc2[r].y;
    __syncthreads();   // all pbuf reads done before red (aliased) writes
    if (wv > 0) {
      #pragma unroll
      for (int r=0;r<ROWS;r++) red[wv-1][r][l] = acc[r];
    }
    __syncthreads();
    if (wv == 0) {
      #pragma unroll
      for (int r=0;r<ROWS;r++) {
        float tot = acc[r] + red[0][r][l] + red[1][r][l] + red[2][r][l];
        ao[((size_t)(b*SEQ + qbase + r))*DM + h*HD + l] = tot / rowsum[r];
      }
    }
  }
}

// ---------------- K4: output projection + bias (128x64 tile, packed FMA) ----------------
__global__ __launch_bounds__(256) void k_proj(const float* __restrict__ aoin, const float* __restrict__ w,
                                              const float* __restrict__ bias, float* __restrict__ out) {
  __shared__ __align__(16) float As[32][128];   // 16KB
  __shared__ __align__(16) float Bs[32][64];    // 8KB
  int tid = threadIdx.x;
  int bm = blockIdx.x, bn = blockIdx.y;
  int ty = tid >> 4, tx = tid & 15;
  v2f acc2[8][2];
  #pragma unroll
  for (int i=0;i<8;i++) { acc2[i][0] = mkv2(0.f,0.f); acc2[i][1] = mkv2(0.f,0.f); }
  for (int kt=0; kt<16; ++kt) {
    #pragma unroll
    for (int q4=0;q4<4;q4++) {
      int f = tid*4+q4; int row = f>>3; int cc = (f&7)*4;   // row 0..127
      float4 ga = *(const float4*)&aoin[(size_t)(bm*128+row)*DM + kt*32 + cc];
      As[cc+0][row]=ga.x; As[cc+1][row]=ga.y; As[cc+2][row]=ga.z; As[cc+3][row]=ga.w;
    }
    #pragma unroll
    for (int q4=0;q4<2;q4++) {
      int f = tid*2+q4; int row = f>>3; int cc = (f&7)*4;   // row 0..63
      float4 gb = *(const float4*)&w[(size_t)(bn*64+row)*DM + kt*32 + cc];
      Bs[cc+0][row]=gb.x; Bs[cc+1][row]=gb.y; Bs[cc+2][row]=gb.z; Bs[cc+3][row]=gb.w;
    }
    __syncthreads();
    #pragma unroll
    for (int kk=0;kk<32;kk++) {
      float4 a0 = *(const float4*)&As[kk][ty*8];
      float4 a1 = *(const float4*)&As[kk][ty*8+4];
      float4 b4 = *(const float4*)&Bs[kk][tx*4];
      float av[8] = {a0.x,a0.y,a0.z,a0.w,a1.x,a1.y,a1.z,a1.w};
      v2f b01 = mkv2(b4.x,b4.y), b23 = mkv2(b4.z,b4.w);
      #pragma unroll
      for (int i=0;i<8;i++) {
        v2f s = mkv2(av[i], av[i]);
        acc2[i][0] = __builtin_elementwise_fma(s, b01, acc2[i][0]);
        acc2[i][1] = __builtin_elementwise_fma(s, b23, acc2[i][1]);
      }
    }
    __syncthreads();
  }
  int o0 = bn*64 + tx*4;
  float4 bvv = *(const float4*)&bias[o0];
  #pragma unroll
  for (int i=0;i<8;i++) {
    int tok = bm*128 + ty*8 + i;
    float4 o;
    o.x = acc2[i][0].x + bvv.x; o.y = acc2[i][0].y + bvv.y;
    o.z = acc2[i][1].x + bvv.z; o.w = acc2[i][1].y + bvv.w;
    *(float4*)&out[(size_t)tok*DM + o0] = o;
  }
}

// ---------------- launch ----------------
extern "C" void kernel_launch(void* const* d_in, const int* in_sizes, int n_in,
                              void* d_out, int out_size, void* d_ws, size_t ws_size,
                              hipStream_t stream) {
  const float* x        = (const float*)d_in[0];
  const int*   mask     = (const int*)  d_in[1];
  const float* qkv_w    = (const float*)d_in[2];
  const float* proj_w   = (const float*)d_in[3];
  const float* proj_b   = (const float*)d_in[4];
  const float* ps_w1    = (const float*)d_in[5];
  const float* ps_b1    = (const float*)d_in[6];
  const float* ps_w2    = (const float*)d_in[7];
  const float* ps_b2    = (const float*)d_in[8];
  const float* ps_w3    = (const float*)d_in[9];
  const float* ps_b3    = (const float*)d_in[10];
  const float* pbias    = (const float*)d_in[11];
  const float* sparse_w = (const float*)d_in[12];
  const float* sparse_b = (const float*)d_in[13];
  float* ws  = (float*)d_ws;
  float* out = (float*)d_out;

  const bool use_jit = (ws_size >= WS_NEED_BYTES);

  k_pool<<<dim3(NB,8), 512, 0, stream>>>(x, ws + OFF_PART);
  k_pattern<<<NB, 512, 0, stream>>>(ws + OFF_PART, mask, ps_w1, ps_b1, ps_w2, ps_b2,
                                    ps_w3, ps_b3, pbias, ws + OFF_CMB, (int*)(ws + OFF_MSUM));
  if (use_jit) k_jit<<<65536, 256, 0, stream>>>(ws + OFF_JIT);
  k_qkv<<<dim3(32,24), 256, 0, stream>>>(x, qkv_w, ws);
  if (use_jit) {
    k_attn<1><<<NB*NH*(SEQ/ROWS), 256, 0, stream>>>(ws + OFF_Q, ws + OFF_KT, ws + OFF_VT, mask,
                                                    ws + OFF_CMB, (const int*)(ws + OFF_MSUM),
                                                    sparse_w, sparse_b, ws + OFF_JIT, ws + OFF_AO);
  } else {
    k_attn<0><<<NB*NH*(SEQ/ROWS), 256, 0, stream>>>(ws + OFF_Q, ws + OFF_KT, ws + OFF_VT, mask,
                                                    ws + OFF_CMB, (const int*)(ws + OFF_MSUM),
                                                    sparse_w, sparse_b, ws + OFF_JIT, ws + OFF_AO);
  }
  k_proj<<<dim3(32,8), 256, 0, stream>>>(ws + OFF_AO, proj_w, proj_b, out);
}

// Round 11
// 430.294 us; speedup vs baseline: 1.2672x; 1.0639x over previous
//
#include <hip/hip_runtime.h>
#include <math.h>

// Problem constants
#define NB   4
#define NH   8
#define SEQ  1024
#define DM   512
#define HD   64
#define WANT 715      // 0-indexed rank of the 716th-largest (kk = int(1024*0.7) = 716)
#define ROWS 8        // query rows per attention block (ROWS=4 regressed: scratch round-trip, r7)

typedef float v2f __attribute__((ext_vector_type(2)));
__device__ __forceinline__ v2f mkv2(float a, float b){ v2f r; r.x=a; r.y=b; return r; }

// ws layout (float offsets)
#define OFF_Q    0u        // (B,H,L,64)  q
#define OFF_KT   2097152u  // (B,H,64,L)  k transposed (fp32)
#define OFF_V    4194304u  // (B,H,L,64)  v natural layout (r11: transposed V was 64-line
                           //   fragmented loads in PV; natural is coalesced, 4x fewer L2 reqs)
#define OFF_AO   6291456u  // (B,L,512)   attention output (pre-proj)
#define OFF_PART 8388608u  // (B,8,512)   pooling partials
#define OFF_CMB  8404992u  // (B,4)       combined-mask values {c00,c10,c01,c11}
#define OFF_MSUM 8405008u  // (B,)        int mask row-sums
#define OFF_JIT  8405504u  // (2^25,)     precomputed jitter (optional, ws_size permitting)
#define WS_NEED_BYTES ((size_t)(OFF_JIT + 33554432u) * 4u)

// ---------------- jitter replication: jax.random.normal(key(42), ...) -----------

__device__ __forceinline__ unsigned rotl32(unsigned x, int r){ return (x<<r)|(x>>(32-r)); }

__device__ __forceinline__ uint2 threefry_0_42(unsigned x0, unsigned x1){
  const unsigned ks0=0u, ks1=42u, ks2=0x1BD11BDAu^42u;
  x0+=ks0; x1+=ks1;
#define TFR(r) { x0+=x1; x1=rotl32(x1,(r)); x1^=x0; }
  TFR(13) TFR(15) TFR(26) TFR(6)
  x0+=ks1; x1+=ks2+1u;
  TFR(17) TFR(29) TFR(16) TFR(24)
  x0+=ks2; x1+=ks0+2u;
  TFR(13) TFR(15) TFR(26) TFR(6)
  x0+=ks0; x1+=ks1+3u;
  TFR(17) TFR(29) TFR(16) TFR(24)
  x0+=ks1; x1+=ks2+4u;
  TFR(13) TFR(15) TFR(26) TFR(6)
  x0+=ks2; x1+=ks0+5u;
#undef TFR
  return make_uint2(x0,x1);
}

// XLA ErfInv32 (Giles) — fast-log variant (jitter tolerates ~1e-3 rel error;
// top-k order only flips for s-gaps < ~1e-9, essentially never)
__device__ __forceinline__ float erfinv_xla(float x){
  float w = -__logf(fmaf(-x, x, 1.0f));
  float p;
  if (w < 5.0f) {
    w -= 2.5f;
    p = 2.81022636e-08f;
    p = fmaf(p,w, 3.43273939e-07f);
    p = fmaf(p,w,-3.5233877e-06f);
    p = fmaf(p,w,-4.39150654e-06f);
    p = fmaf(p,w, 0.00021858087f);
    p = fmaf(p,w,-0.00125372503f);
    p = fmaf(p,w,-0.00417768164f);
    p = fmaf(p,w, 0.246640727f);
    p = fmaf(p,w, 1.50140941f);
  } else {
    w = sqrtf(w) - 3.0f;
    p = -0.000200214257f;
    p = fmaf(p,w, 0.000100950558f);
    p = fmaf(p,w, 0.00134934322f);
    p = fmaf(p,w,-0.00367342844f);
    p = fmaf(p,w, 0.00573950773f);
    p = fmaf(p,w,-0.0076224613f);
    p = fmaf(p,w, 0.00943887047f);
    p = fmaf(p,w, 1.00167406f);
    p = fmaf(p,w, 2.83297682f);
  }
  return p*x;
}

__device__ __forceinline__ float norm_from_bits(unsigned bits){
  float fl = __uint_as_float((bits >> 9) | 0x3F800000u) - 1.0f; // [0,1)
  float u  = fmaf(fl, 2.0f, -0.99999994f);
  u = fmaxf(-0.99999994f, u);
  return (1.41421356f * erfinv_xla(u)) * 1e-6f;
}

// jitter element at flat index f of the (4,8,1024,1024) normal draw, times 1e-6.
__device__ __forceinline__ float jitter_val(unsigned f){
  unsigned i   = f & 0xFFFFFFu;
  unsigned sel = f >> 24;
  uint2 rr = threefry_0_42(i, i + 0x1000000u);
  return norm_from_bits(sel ? rr.y : rr.x);
}

// ---------------- K0: pooling partials ----------------
__global__ __launch_bounds__(512) void k_pool(const float* __restrict__ x, float* __restrict__ part) {
  int b = blockIdx.x, ch = blockIdx.y, c = threadIdx.x;
  const float* xp = x + ((size_t)(b*SEQ + ch*128))*DM + c;
  float s = 0.f;
  for (int l=0;l<128;l++) s += xp[(size_t)l*DM];
  part[(b*8+ch)*DM + c] = s;
}

// ---------------- K1: pattern-selector MLP -> combined-mask values ----------------
__global__ __launch_bounds__(512) void k_pattern(const float* __restrict__ part, const int* __restrict__ mask,
    const float* __restrict__ w1, const float* __restrict__ b1,
    const float* __restrict__ w2, const float* __restrict__ b2,
    const float* __restrict__ w3, const float* __restrict__ b3,
    const float* __restrict__ pbias, float* __restrict__ cmb, int* __restrict__ msum) {
  __shared__ __align__(16) float pooled[DM];
  __shared__ __align__(16) float h1[DM];
  __shared__ __align__(16) float h2[DM/2];
  __shared__ float lg[3];
  __shared__ int msum_s;
  int b = blockIdx.x, t = threadIdx.x;
  float p = 0.f;
  for (int ch=0; ch<8; ++ch) p += part[(b*8+ch)*DM + t];
  pooled[t] = p * (1.0f/1024.0f);
  if (t == 0) msum_s = 0;
  __syncthreads();
  atomicAdd(&msum_s, mask[b*SEQ + t] + mask[b*SEQ + 512 + t]);
  // h1 = relu(pooled @ w1.T + b1)  (float4 loads, scalar ascending adds -> bit-identical)
  {
    float a = 0.f; const float4* wr = (const float4*)(w1 + (size_t)t*DM);
    const float4* pp = (const float4*)pooled;
    for (int c4=0;c4<DM/4;c4++) {
      float4 wv4 = wr[c4], pv4 = pp[c4];
      a += wv4.x*pv4.x; a += wv4.y*pv4.y; a += wv4.z*pv4.z; a += wv4.w*pv4.w;
    }
    a += b1[t];
    h1[t] = fmaxf(a, 0.f);
  }
  __syncthreads();
  if (t < 256) {
    float a = 0.f; const float4* wr = (const float4*)(w2 + (size_t)t*DM);
    const float4* hh = (const float4*)h1;
    for (int c4=0;c4<DM/4;c4++) {
      float4 wv4 = wr[c4], hv4 = hh[c4];
      a += wv4.x*hv4.x; a += wv4.y*hv4.y; a += wv4.z*hv4.z; a += wv4.w*hv4.w;
    }
    a += b2[t];
    h2[t] = fmaxf(a, 0.f);
  }
  __syncthreads();
  if (t < 3) {
    float a = 0.f; const float4* wr = (const float4*)(w3 + t*256);
    const float4* hh = (const float4*)h2;
    for (int c4=0;c4<64;c4++) {
      float4 wv4 = wr[c4], hv4 = hh[c4];
      a += wv4.x*hv4.x; a += wv4.y*hv4.y; a += wv4.z*hv4.z; a += wv4.w*hv4.w;
    }
    a += b3[t] + pbias[t];
    lg[t] = a * 2.0f;      // /PTEMP (0.5)
  }
  __syncthreads();
  if (t == 0) {
    float m = fmaxf(lg[0], fmaxf(lg[1], lg[2]));
    float e0 = expf(lg[0]-m), e1 = expf(lg[1]-m), e2 = expf(lg[2]-m);
    float Z = e0+e1+e2;
    float pw0 = e0/Z, pw1 = e1/Z, pw2 = e2/Z;
    cmb[b*4+0] = pw1;
    cmb[b*4+1] = pw0 + pw1;
    cmb[b*4+2] = pw1 + pw2;
    cmb[b*4+3] = (pw0 + pw1) + pw2;
    msum[b] = msum_s;
  }
}

// ---------------- K2: FUSED QKV projection + jitter precompute ----------------
// Blocks 0..767: the r10 qkv GEMM (dispatched first -> resident early, 3/CU);
// blocks 768+: jitter precompute fills the remaining wave slots, overlapping
// qkv's memory stalls instead of serializing after it. Disjoint outputs.
// qkv math identical to r10 (packed-pair acc, bit-identical q/k/v). V stored natural.
__global__ __launch_bounds__(256) void k_qkv_jit(const float* __restrict__ x, const float* __restrict__ w,
                                                 float* __restrict__ ws, float* __restrict__ jit) {
  __shared__ __align__(16) float As[32][128];   // 16KB
  __shared__ __align__(16) float Bs[32][64];    // 8KB
  int tid = threadIdx.x;
  if (blockIdx.x >= 768) {
    unsigned i = (blockIdx.x - 768u)*256u + tid;
    uint2 rr = threefry_0_42(i, i + 0x1000000u);
    jit[i]              = norm_from_bits(rr.x);
    jit[i + 0x1000000u] = norm_from_bits(rr.y);
    return;
  }
  int bm = blockIdx.x & 31, bn = blockIdx.x >> 5;
  int ty = tid >> 4, tx = tid & 15;
  v2f acc2[8][2];
  #pragma unroll
  for (int i=0;i<8;i++) { acc2[i][0] = mkv2(0.f,0.f); acc2[i][1] = mkv2(0.f,0.f); }
  for (int kt=0; kt<16; ++kt) {
    #pragma unroll
    for (int q4=0;q4<4;q4++) {
      int f = tid*4+q4; int row = f>>3; int cc = (f&7)*4;   // row 0..127
      float4 ga = *(const float4*)&x[(size_t)(bm*128+row)*DM + kt*32 + cc];
      As[cc+0][row]=ga.x; As[cc+1][row]=ga.y; As[cc+2][row]=ga.z; As[cc+3][row]=ga.w;
    }
    #pragma unroll
    for (int q4=0;q4<2;q4++) {
      int f = tid*2+q4; int row = f>>3; int cc = (f&7)*4;   // row 0..63
      float4 gb = *(const float4*)&w[(size_t)(bn*64+row)*DM + kt*32 + cc];
      Bs[cc+0][row]=gb.x; Bs[cc+1][row]=gb.y; Bs[cc+2][row]=gb.z; Bs[cc+3][row]=gb.w;
    }
    __syncthreads();
    #pragma unroll
    for (int kk=0;kk<32;kk++) {
      float4 a0 = *(const float4*)&As[kk][ty*8];
      float4 a1 = *(const float4*)&As[kk][ty*8+4];
      float4 b4 = *(const float4*)&Bs[kk][tx*4];
      float av[8] = {a0.x,a0.y,a0.z,a0.w,a1.x,a1.y,a1.z,a1.w};
      v2f b01 = mkv2(b4.x,b4.y), b23 = mkv2(b4.z,b4.w);
      #pragma unroll
      for (int i=0;i<8;i++) {
        v2f s = mkv2(av[i], av[i]);
        acc2[i][0] = __builtin_elementwise_fma(s, b01, acc2[i][0]);
        acc2[i][1] = __builtin_elementwise_fma(s, b23, acc2[i][1]);
      }
    }
    __syncthreads();
  }
  float acc[8][4];
  #pragma unroll
  for (int i=0;i<8;i++) {
    acc[i][0]=acc2[i][0].x; acc[i][1]=acc2[i][0].y;
    acc[i][2]=acc2[i][1].x; acc[i][3]=acc2[i][1].y;
  }
  int m0 = bn*64;
  int s = m0 >> 9;
  int h = (m0 >> 6) & 7;
  int b = bm >> 3;               // 8 blocks of 128 tokens per batch
  int l0 = (bm & 7) * 128;
  int d0 = tx*4;
  if (s == 0 || s == 2) {
    unsigned off = (s == 0) ? OFF_Q : OFF_V;   // row-major (L,64) for both
    #pragma unroll
    for (int i=0;i<8;i++) {
      int l = l0 + ty*8 + i;
      float4 o = {acc[i][0],acc[i][1],acc[i][2],acc[i][3]};
      *(float4*)&ws[off + ((size_t)((b*NH+h)*SEQ + l))*HD + d0] = o;
    }
  } else {
    size_t base = OFF_KT + ((size_t)((b*NH+h)*HD))*SEQ;
    #pragma unroll
    for (int j=0;j<4;j++) {
      float4 c0 = {acc[0][j], acc[1][j], acc[2][j], acc[3][j]};
      float4 c1 = {acc[4][j], acc[5][j], acc[6][j], acc[7][j]};
      size_t cb = base + (size_t)(d0+j)*SEQ + l0 + ty*8;
      *(float4*)&ws[cb]     = c0;
      *(float4*)&ws[cb + 4] = c1;
    }
  }
}

// ---------------- K3: fused scores + jitter + top-k select + softmax + PV ----------------
// r10 structure; P5 now reads V in natural (SEQ,HD) layout: lane l loads V[j][l] --
// scalar, perfectly coalesced (4 lines/inst vs 64 for transposed-V float4).
// Same values, same packed-fma sequence -> bit-identical.
template<int USEJIT>
__global__ __launch_bounds__(256, 4) void k_attn(
    const float* __restrict__ ws_q, const float* __restrict__ ws_kT, const float* __restrict__ ws_v,
    const int* __restrict__ mask, const float* __restrict__ cmb, const int* __restrict__ msum,
    const float* __restrict__ sparse_w, const float* __restrict__ sparse_b,
    const float* __restrict__ jit, float* __restrict__ ao) {
  __shared__ __align__(16) float pbuf[ROWS][SEQ];      // 32KB; aliased: hist (8KB, P3), red (6KB, P5 tail)
  __shared__ __align__(16) float q_s[ROWS][HD];        // 2KB
  __shared__ float mxred[4][ROWS], smred[4][ROWS];
  __shared__ unsigned pfx_s[ROWS];
  __shared__ int want_s[ROWS];
  __shared__ float mxrow[ROWS], rowsum[ROWS];
  __shared__ float cmb_s[4];

  unsigned* hist = (unsigned*)&pbuf[0][0];             // [ROWS*256] = 8KB (P3 only)
  float (*red)[ROWS][HD] = (float (*)[ROWS][HD])&pbuf[0][0]; // [3][ROWS][HD] (P5 tail only)

  int tid = threadIdx.x;
  int gid = blockIdx.x;
  int bh = gid >> 7;            // 0..31
  int rt = gid & 127;
  int b = bh >> 3, h = bh & 7;
  int qbase = rt * ROWS;

  // P0: stage q rows + combined values + init select state
  {
    const float* qp = ws_q + ((size_t)bh*SEQ + qbase)*HD;
    if (tid < 128) ((float4*)q_s)[tid] = ((const float4*)qp)[tid];
    if (tid < 4) cmb_s[tid] = cmb[b*4+tid];
    if (tid < ROWS) { pfx_s[tid] = 0u; want_s[tid] = WANT; }
  }
  __syncthreads();

  // P1: scores -> registers. score[c][r] for key j=tid*4+c, row r.
  float score[4][ROWS];
  {
    const float* kT = ws_kT + (size_t)bh*HD*SEQ;
    #pragma unroll
    for (int c=0;c<4;c++)
      #pragma unroll
      for (int r=0;r<ROWS;r++) score[c][r]=0.f;
    for (int d4=0; d4<16; ++d4) {
      float4 qv[ROWS];
      #pragma unroll
      for (int r=0;r<ROWS;r++) qv[r] = *(const float4*)&q_s[r][d4*4];
      float4 ka = *(const float4*)&kT[(size_t)(d4*4+0)*SEQ + tid*4];
      float4 kb = *(const float4*)&kT[(size_t)(d4*4+1)*SEQ + tid*4];
      float4 kc = *(const float4*)&kT[(size_t)(d4*4+2)*SEQ + tid*4];
      float4 kd = *(const float4*)&kT[(size_t)(d4*4+3)*SEQ + tid*4];
      #pragma unroll
      for (int r=0;r<ROWS;r++) {
        score[0][r] += qv[r].x*ka.x + qv[r].y*kb.x + qv[r].z*kc.x + qv[r].w*kd.x;
        score[1][r] += qv[r].x*ka.y + qv[r].y*kb.y + qv[r].z*kc.y + qv[r].w*kd.y;
        score[2][r] += qv[r].x*ka.z + qv[r].y*kb.z + qv[r].z*kc.z + qv[r].w*kd.z;
        score[3][r] += qv[r].x*ka.w + qv[r].y*kb.w + qv[r].z*kc.w + qv[r].w*kd.w;
      }
    }
    #pragma unroll
    for (int c=0;c<4;c++)
      #pragma unroll
      for (int r=0;r<ROWS;r++)
        score[c][r] *= 0.125f;   // * hd^-0.5
  }

  // P2: sortable(s + jitter) -> registers
  unsigned u[4][ROWS];
  {
    float sw = sparse_w[h], sb = sparse_b[h];
    #pragma unroll
    for (int r=0;r<ROWS;r++) {
      unsigned fbase = ((unsigned)bh << 20) + ((unsigned)(qbase + r) << 10);
      float jv[4];
      if (USEJIT) {
        float4 j4 = *(const float4*)&jit[fbase + (unsigned)(tid*4)];
        jv[0]=j4.x; jv[1]=j4.y; jv[2]=j4.z; jv[3]=j4.w;
      } else {
        #pragma unroll
        for (int c=0;c<4;c++) jv[c] = jitter_val(fbase + (unsigned)(tid*4+c));
      }
      #pragma unroll
      for (int c=0;c<4;c++) {
        float s = score[c][r]*sw + sb + jv[c];
        unsigned bu = __float_as_uint(s);
        u[c][r] = (bu & 0x80000000u) ? ~bu : (bu | 0x80000000u);
      }
    }
  }

  // P3: exact 716th-largest per row via 4-pass radix select (values from registers).
  // Pass 0 dedups the all-equal-digit case (counts identical, fewer same-addr atomics).
  {
    int r2 = tid >> 5, w = tid & 31;    // 32 threads scan per row
    for (int pass=0; pass<4; ++pass) {
      int shift = 24 - 8*pass;
      for (int e = tid; e < ROWS*256; e += 256) hist[e] = 0u;
      __syncthreads();
      if (pass == 0) {
        #pragma unroll
        for (int r=0;r<ROWS;r++) {
          unsigned a = u[0][r] >> 24, bb = u[1][r] >> 24,
                   cc = u[2][r] >> 24, dd = u[3][r] >> 24;
          if (a == bb && a == cc && a == dd) {
            atomicAdd(&hist[r*256 + a], 4u);
          } else {
            atomicAdd(&hist[r*256 + a], 1u);
            atomicAdd(&hist[r*256 + bb], 1u);
            atomicAdd(&hist[r*256 + cc], 1u);
            atomicAdd(&hist[r*256 + dd], 1u);
          }
        }
      } else {
        unsigned hmask = 0xFFFFFFFFu << (shift+8);
        #pragma unroll
        for (int r=0;r<ROWS;r++) {
          unsigned pf = pfx_s[r];
          #pragma unroll
          for (int c=0;c<4;c++) {
            unsigned uu = u[c][r];
            if ((uu & hmask) == pf) atomicAdd(&hist[r*256 + ((uu>>shift)&255u)], 1u);
          }
        }
      }
      __syncthreads();
      unsigned cs = 0;
      #pragma unroll
      for (int k=0;k<8;k++) cs += hist[r2*256 + w*8 + k];
      unsigned is = cs;
      #pragma unroll
      for (int off=1; off<32; off<<=1) {
        unsigned tt = __shfl_down(is, off, 32);
        if (w + off < 32) is += tt;
      }
      unsigned es = is - cs;   // count in strictly-higher chunks
      int want = want_s[r2];
      if ((int)es <= want && want < (int)(es + cs)) {
        int cacc = (int)es;
        for (int k=7;k>=0;k--) {
          unsigned hc = hist[r2*256 + w*8 + k];
          if (want < cacc + (int)hc) {
            pfx_s[r2] |= ((unsigned)(w*8+k)) << shift;
            want_s[r2] = want - cacc;
            break;
          }
          cacc += (int)hc;
        }
      }
      __syncthreads();
    }
  }

  // pack sparse-select bits, freeing u[]
  unsigned spmask = 0u;
  {
    #pragma unroll
    for (int r=0;r<ROWS;r++) {
      unsigned Tr = pfx_s[r];
      #pragma unroll
      for (int c=0;c<4;c++)
        if (u[c][r] >= Tr) spmask |= 1u << (r*4+c);
    }
  }

  // P4: masking + block-wide softmax; p written to pbuf (float4 per row)
  {
    float c00 = cmb_s[0], c10 = cmb_s[1], c01 = cmb_s[2], c11 = cmb_s[3];
    int msum_b = msum[b];
    const int4 m4 = *(const int4*)&mask[b*SEQ + tid*4];
    int mv[4] = {m4.x, m4.y, m4.z, m4.w};
    bool okm[4];
    #pragma unroll
    for (int c=0;c<4;c++) {
      int j = tid*4 + c;
      okm[c] = (mv[c] != 0) || (msum_b == 0 && j == 0);
    }
    float lmax[ROWS];
    #pragma unroll
    for (int r=0;r<ROWS;r++) {
      int qr = qbase + r;
      float lm = -INFINITY;
      #pragma unroll
      for (int c=0;c<4;c++) {
        int j = tid*4 + c;
        bool sp = (spmask >> (r*4+c)) & 1u;
        int dj = j - qr; dj = dj < 0 ? -dj : dj;
        float comb = (dj <= 16) ? (sp ? c11 : c10) : (sp ? c01 : c00);
        float val = (comb > 0.1f && okm[c]) ? score[c][r] : -INFINITY;
        score[c][r] = val;
        lm = fmaxf(lm, val);
      }
      lmax[r] = lm;
    }
    #pragma unroll
    for (int r=0;r<ROWS;r++)
      #pragma unroll
      for (int off=32; off>=1; off>>=1)
        lmax[r] = fmaxf(lmax[r], __shfl_xor(lmax[r], off, 64));
    int wv = tid >> 6, lane = tid & 63;
    if (lane == 0) {
      #pragma unroll
      for (int r=0;r<ROWS;r++) mxred[wv][r] = lmax[r];
    }
    __syncthreads();
    if (tid < ROWS)
      mxrow[tid] = fmaxf(fmaxf(mxred[0][tid], mxred[1][tid]), fmaxf(mxred[2][tid], mxred[3][tid]));
    __syncthreads();
    float lsum[ROWS];
    #pragma unroll
    for (int r=0;r<ROWS;r++) {
      float M = mxrow[r];
      bool allm = (M == -INFINITY);
      float p0, p1, p2, p3;
      if (allm) {
        p0 = (tid == 0) ? 1.0f : 0.0f; p1 = 0.f; p2 = 0.f; p3 = 0.f;
      } else {
        p0 = __expf(score[0][r] - M);
        p1 = __expf(score[1][r] - M);
        p2 = __expf(score[2][r] - M);
        p3 = __expf(score[3][r] - M);
      }
      float4 pv = {p0,p1,p2,p3};
      *(float4*)&pbuf[r][tid*4] = pv;
      lsum[r] = p0+p1+p2+p3;
    }
    #pragma unroll
    for (int r=0;r<ROWS;r++)
      #pragma unroll
      for (int off=32; off>=1; off>>=1)
        lsum[r] += __shfl_xor(lsum[r], off, 64);
    if (lane == 0) {
      #pragma unroll
      for (int r=0;r<ROWS;r++) smred[wv][r] = lsum[r];
    }
    __syncthreads();
    if (tid < ROWS)
      rowsum[tid] = smred[0][tid] + smred[1][tid] + smred[2][tid] + smred[3][tid];
  }
  __syncthreads();

  // P5: PV with packed v2f accumulators; V natural layout -> lane l reads V[j][l]
  // (coalesced scalar loads). p reads are wave-uniform LDS broadcasts.
  // red aliases pbuf (written only after all reads).
  {
    int wv = tid >> 6, l = tid & 63;
    const float* vrow = ws_v + ((size_t)bh*SEQ)*HD + l;
    float acc[ROWS];
    v2f acc2[ROWS];
    #pragma unroll
    for (int r=0;r<ROWS;r++) acc2[r] = mkv2(0.f,0.f);
    int jb = wv*256;
    for (int j8=0;j8<32;j8++) {
      int j = jb + j8*8;
      float v0 = vrow[(size_t)(j+0)*HD];
      float v1 = vrow[(size_t)(j+1)*HD];
      float v2 = vrow[(size_t)(j+2)*HD];
      float v3 = vrow[(size_t)(j+3)*HD];
      float v4 = vrow[(size_t)(j+4)*HD];
      float v5 = vrow[(size_t)(j+5)*HD];
      float v6 = vrow[(size_t)(j+6)*HD];
      float v7 = vrow[(size_t)(j+7)*HD];
      v2f va01 = mkv2(v0,v1), va23 = mkv2(v2,v3);
      v2f vb01 = mkv2(v4,v5), vb23 = mkv2(v6,v7);
      #pragma unroll
      for (int r=0;r<ROWS;r++) {
        float4 pa = *(const float4*)&pbuf[r][j];
        float4 pb = *(const float4*)&pbuf[r][j+4];
        v2f t = acc2[r];
        t = __builtin_elementwise_fma(mkv2(pa.x,pa.y), va01, t);
        t = __builtin_elementwise_fma(mkv2(pa.z,pa.w), va23, t);
        t = __builtin_elementwise_fma(mkv2(pb.x,pb.y), vb01, t);
        t = __builtin_elementwise_fma(mkv2(pb.z,pb.w), vb23, t);
        acc2[r] = t;
      }
    }
    #pragma unroll
    for (int r=0;r<ROWS;r++) acc[r] = acc2[r].x + acc2[r].y;
    __syncthreads();   // all pbuf reads done before red (aliased) writes
    if (wv > 0) {
      #pragma unroll
      for (int r=0;r<ROWS;r++) red[wv-1][r][l] = acc[r];
    }
    __syncthreads();
    if (wv == 0) {
      #pragma unroll
      for (int r=0;r<ROWS;r++) {
        float tot = acc[r] + red[0][r][l] + red[1][r][l] + red[2][r][l];
        ao[((size_t)(b*SEQ + qbase + r))*DM + h*HD + l] = tot / rowsum[r];
      }
    }
  }
}

// ---------------- K4: output projection + bias (128x64 tile, packed FMA) ----------------
__global__ __launch_bounds__(256) void k_proj(const float* __restrict__ aoin, const float* __restrict__ w,
                                              const float* __restrict__ bias, float* __restrict__ out) {
  __shared__ __align__(16) float As[32][128];   // 16KB
  __shared__ __align__(16) float Bs[32][64];    // 8KB
  int tid = threadIdx.x;
  int bm = blockIdx.x, bn = blockIdx.y;
  int ty = tid >> 4, tx = tid & 15;
  v2f acc2[8][2];
  #pragma unroll
  for (int i=0;i<8;i++) { acc2[i][0] = mkv2(0.f,0.f); acc2[i][1] = mkv2(0.f,0.f); }
  for (int kt=0; kt<16; ++kt) {
    #pragma unroll
    for (int q4=0;q4<4;q4++) {
      int f = tid*4+q4; int row = f>>3; int cc = (f&7)*4;   // row 0..127
      float4 ga = *(const float4*)&aoin[(size_t)(bm*128+row)*DM + kt*32 + cc];
      As[cc+0][row]=ga.x; As[cc+1][row]=ga.y; As[cc+2][row]=ga.z; As[cc+3][row]=ga.w;
    }
    #pragma unroll
    for (int q4=0;q4<2;q4++) {
      int f = tid*2+q4; int row = f>>3; int cc = (f&7)*4;   // row 0..63
      float4 gb = *(const float4*)&w[(size_t)(bn*64+row)*DM + kt*32 + cc];
      Bs[cc+0][row]=gb.x; Bs[cc+1][row]=gb.y; Bs[cc+2][row]=gb.z; Bs[cc+3][row]=gb.w;
    }
    __syncthreads();
    #pragma unroll
    for (int kk=0;kk<32;kk++) {
      float4 a0 = *(const float4*)&As[kk][ty*8];
      float4 a1 = *(const float4*)&As[kk][ty*8+4];
      float4 b4 = *(const float4*)&Bs[kk][tx*4];
      float av[8] = {a0.x,a0.y,a0.z,a0.w,a1.x,a1.y,a1.z,a1.w};
      v2f b01 = mkv2(b4.x,b4.y), b23 = mkv2(b4.z,b4.w);
      #pragma unroll
      for (int i=0;i<8;i++) {
        v2f s = mkv2(av[i], av[i]);
        acc2[i][0] = __builtin_elementwise_fma(s, b01, acc2[i][0]);
        acc2[i][1] = __builtin_elementwise_fma(s, b23, acc2[i][1]);
      }
    }
    __syncthreads();
  }
  int o0 = bn*64 + tx*4;
  float4 bvv = *(const float4*)&bias[o0];
  #pragma unroll
  for (int i=0;i<8;i++) {
    int tok = bm*128 + ty*8 + i;
    float4 o;
    o.x = acc2[i][0].x + bvv.x; o.y = acc2[i][0].y + bvv.y;
    o.z = acc2[i][1].x + bvv.z; o.w = acc2[i][1].y + bvv.w;
    *(float4*)&out[(size_t)tok*DM + o0] = o;
  }
}

// ---------------- launch ----------------
extern "C" void kernel_launch(void* const* d_in, const int* in_sizes, int n_in,
                              void* d_out, int out_size, void* d_ws, size_t ws_size,
                              hipStream_t stream) {
  const float* x        = (const float*)d_in[0];
  const int*   mask     = (const int*)  d_in[1];
  const float* qkv_w    = (const float*)d_in[2];
  const float* proj_w   = (const float*)d_in[3];
  const float* proj_b   = (const float*)d_in[4];
  const float* ps_w1    = (const float*)d_in[5];
  const float* ps_b1    = (const float*)d_in[6];
  const float* ps_w2    = (const float*)d_in[7];
  const float* ps_b2    = (const float*)d_in[8];
  const float* ps_w3    = (const float*)d_in[9];
  const float* ps_b3    = (const float*)d_in[10];
  const float* pbias    = (const float*)d_in[11];
  const float* sparse_w = (const float*)d_in[12];
  const float* sparse_b = (const float*)d_in[13];
  float* ws  = (float*)d_ws;
  float* out = (float*)d_out;

  const bool use_jit = (ws_size >= WS_NEED_BYTES);

  k_pool<<<dim3(NB,8), 512, 0, stream>>>(x, ws + OFF_PART);
  k_pattern<<<NB, 512, 0, stream>>>(ws + OFF_PART, mask, ps_w1, ps_b1, ps_w2, ps_b2,
                                    ps_w3, ps_b3, pbias, ws + OFF_CMB, (int*)(ws + OFF_MSUM));
  // fused: blocks 0..767 = qkv GEMM; blocks 768.. = jitter precompute (overlap)
  k_qkv_jit<<<use_jit ? 66304 : 768, 256, 0, stream>>>(x, qkv_w, ws, ws + OFF_JIT);
  if (use_jit) {
    k_attn<1><<<NB*NH*(SEQ/ROWS), 256, 0, stream>>>(ws + OFF_Q, ws + OFF_KT, ws + OFF_V, mask,
                                                    ws + OFF_CMB, (const int*)(ws + OFF_MSUM),
                                                    sparse_w, sparse_b, ws + OFF_JIT, ws + OFF_AO);
  } else {
    k_attn<0><<<NB*NH*(SEQ/ROWS), 256, 0, stream>>>(ws + OFF_Q, ws + OFF_KT, ws + OFF_V, mask,
                                                    ws + OFF_CMB, (const int*)(ws + OFF_MSUM),
                                                    sparse_w, sparse_b, ws + OFF_JIT, ws + OFF_AO);
  }
  k_proj<<<dim3(32,8), 256, 0, stream>>>(ws + OFF_AO, proj_w, proj_b, out);
}

// Round 12
// 379.625 us; speedup vs baseline: 1.4363x; 1.1335x over previous
//
#include <hip/hip_runtime.h>
#include <math.h>

// Problem constants
#define NB   4
#define NH   8
#define SEQ  1024
#define DM   512
#define HD   64
#define WANT 715      // 0-indexed rank of the 716th-largest (kk = int(1024*0.7) = 716)
#define ROWS 8        // query rows per attention block (ROWS=4 regressed: scratch round-trip, r7)
#define HSTRIDE (ROWS*256 + 8)   // 2-copy histogram stride: copy1 banks shifted by 8

typedef float v2f __attribute__((ext_vector_type(2)));
__device__ __forceinline__ v2f mkv2(float a, float b){ v2f r; r.x=a; r.y=b; return r; }

// ws layout (float offsets)
#define OFF_Q    0u        // (B,H,L,64)  q
#define OFF_KT   2097152u  // (B,H,64,L)  k transposed (fp32)
#define OFF_V    4194304u  // (B,H,L,64)  v natural layout
#define OFF_AO   6291456u  // (B,L,512)   attention output (pre-proj)
#define OFF_PART 8388608u  // (B,8,512)   pooling partials
#define OFF_CMB  8404992u  // (B,4)       combined-mask values {c00,c10,c01,c11}
#define OFF_MSUM 8405008u  // (B,)        int mask row-sums
#define OFF_JIT  8405504u  // (2^25,)     precomputed jitter (optional, ws_size permitting)
#define WS_NEED_BYTES ((size_t)(OFF_JIT + 33554432u) * 4u)

// ---------------- jitter replication: jax.random.normal(key(42), ...) -----------

__device__ __forceinline__ unsigned rotl32(unsigned x, int r){ return (x<<r)|(x>>(32-r)); }

__device__ __forceinline__ uint2 threefry_0_42(unsigned x0, unsigned x1){
  const unsigned ks0=0u, ks1=42u, ks2=0x1BD11BDAu^42u;
  x0+=ks0; x1+=ks1;
#define TFR(r) { x0+=x1; x1=rotl32(x1,(r)); x1^=x0; }
  TFR(13) TFR(15) TFR(26) TFR(6)
  x0+=ks1; x1+=ks2+1u;
  TFR(17) TFR(29) TFR(16) TFR(24)
  x0+=ks2; x1+=ks0+2u;
  TFR(13) TFR(15) TFR(26) TFR(6)
  x0+=ks0; x1+=ks1+3u;
  TFR(17) TFR(29) TFR(16) TFR(24)
  x0+=ks1; x1+=ks2+4u;
  TFR(13) TFR(15) TFR(26) TFR(6)
  x0+=ks2; x1+=ks0+5u;
#undef TFR
  return make_uint2(x0,x1);
}

// XLA ErfInv32 (Giles) — fast-log variant
__device__ __forceinline__ float erfinv_xla(float x){
  float w = -__logf(fmaf(-x, x, 1.0f));
  float p;
  if (w < 5.0f) {
    w -= 2.5f;
    p = 2.81022636e-08f;
    p = fmaf(p,w, 3.43273939e-07f);
    p = fmaf(p,w,-3.5233877e-06f);
    p = fmaf(p,w,-4.39150654e-06f);
    p = fmaf(p,w, 0.00021858087f);
    p = fmaf(p,w,-0.00125372503f);
    p = fmaf(p,w,-0.00417768164f);
    p = fmaf(p,w, 0.246640727f);
    p = fmaf(p,w, 1.50140941f);
  } else {
    w = sqrtf(w) - 3.0f;
    p = -0.000200214257f;
    p = fmaf(p,w, 0.000100950558f);
    p = fmaf(p,w, 0.00134934322f);
    p = fmaf(p,w,-0.00367342844f);
    p = fmaf(p,w, 0.00573950773f);
    p = fmaf(p,w,-0.0076224613f);
    p = fmaf(p,w, 0.00943887047f);
    p = fmaf(p,w, 1.00167406f);
    p = fmaf(p,w, 2.83297682f);
  }
  return p*x;
}

__device__ __forceinline__ float norm_from_bits(unsigned bits){
  float fl = __uint_as_float((bits >> 9) | 0x3F800000u) - 1.0f; // [0,1)
  float u  = fmaf(fl, 2.0f, -0.99999994f);
  u = fmaxf(-0.99999994f, u);
  return (1.41421356f * erfinv_xla(u)) * 1e-6f;
}

// jitter element at flat index f of the (4,8,1024,1024) normal draw, times 1e-6.
__device__ __forceinline__ float jitter_val(unsigned f){
  unsigned i   = f & 0xFFFFFFu;
  unsigned sel = f >> 24;
  uint2 rr = threefry_0_42(i, i + 0x1000000u);
  return norm_from_bits(sel ? rr.y : rr.x);
}

// ---------------- K0: pooling partials ----------------
__global__ __launch_bounds__(512) void k_pool(const float* __restrict__ x, float* __restrict__ part) {
  int b = blockIdx.x, ch = blockIdx.y, c = threadIdx.x;
  const float* xp = x + ((size_t)(b*SEQ + ch*128))*DM + c;
  float s = 0.f;
  for (int l=0;l<128;l++) s += xp[(size_t)l*DM];
  part[(b*8+ch)*DM + c] = s;
}

// ---------------- K2: FUSED pattern-MLP + QKV projection + jitter precompute ----------------
// Blocks 0..3: pattern-selector MLP (b = blockIdx.x), hidden under qkv/jit;
// blocks 4..771: qkv GEMM (r11 math, bit-identical); blocks 772+: jitter.
// Pattern reworked for 256 threads: each thread runs the SAME per-output
// ascending float4 loop for 2 outputs -> bit-identical cmb/msum.
__global__ __launch_bounds__(256) void k_fused(const float* __restrict__ x, const float* __restrict__ w,
    float* __restrict__ ws, float* __restrict__ jit,
    const float* __restrict__ part, const int* __restrict__ mask,
    const float* __restrict__ w1, const float* __restrict__ b1,
    const float* __restrict__ w2, const float* __restrict__ b2,
    const float* __restrict__ w3, const float* __restrict__ b3,
    const float* __restrict__ pbias, float* __restrict__ cmb, int* __restrict__ msum) {
  __shared__ __align__(16) float As[32][128];   // 16KB (pattern aliases into this)
  __shared__ __align__(16) float Bs[32][64];    // 8KB
  int tid = threadIdx.x;

  if (blockIdx.x < 4) {
    // ---- pattern-selector MLP, block b ----
    int b = blockIdx.x;
    float* pooled = &As[0][0];          // 512
    float* h1p    = &As[0][0] + 512;    // 512
    float* h2p    = &As[0][0] + 1024;   // 256
    float* lgp    = &As[0][0] + 1280;   // 3
    int*   msum_s = (int*)(&As[0][0] + 1284);
    if (tid == 0) *msum_s = 0;
    // pooled: per-column ascending-ch sum, same as before
    #pragma unroll
    for (int q=0;q<2;q++) {
      int c = tid + q*256;
      float p = 0.f;
      for (int ch=0; ch<8; ++ch) p += part[(b*8+ch)*DM + c];
      pooled[c] = p * (1.0f/1024.0f);
    }
    __syncthreads();
    {
      int lm = mask[b*SEQ + tid] + mask[b*SEQ + 256 + tid]
             + mask[b*SEQ + 512 + tid] + mask[b*SEQ + 768 + tid];
      atomicAdd(msum_s, lm);
    }
    // h1 = relu(pooled @ w1.T + b1): identical per-output float4 ascending loop
    #pragma unroll
    for (int q=0;q<2;q++) {
      int o = tid + q*256;
      float a = 0.f; const float4* wr = (const float4*)(w1 + (size_t)o*DM);
      const float4* pp = (const float4*)pooled;
      for (int c4=0;c4<DM/4;c4++) {
        float4 wv4 = wr[c4], pv4 = pp[c4];
        a += wv4.x*pv4.x; a += wv4.y*pv4.y; a += wv4.z*pv4.z; a += wv4.w*pv4.w;
      }
      a += b1[o];
      h1p[o] = fmaxf(a, 0.f);
    }
    __syncthreads();
    {
      int o = tid;
      float a = 0.f; const float4* wr = (const float4*)(w2 + (size_t)o*DM);
      const float4* hh = (const float4*)h1p;
      for (int c4=0;c4<DM/4;c4++) {
        float4 wv4 = wr[c4], hv4 = hh[c4];
        a += wv4.x*hv4.x; a += wv4.y*hv4.y; a += wv4.z*hv4.z; a += wv4.w*hv4.w;
      }
      a += b2[o];
      h2p[o] = fmaxf(a, 0.f);
    }
    __syncthreads();
    if (tid < 3) {
      float a = 0.f; const float4* wr = (const float4*)(w3 + tid*256);
      const float4* hh = (const float4*)h2p;
      for (int c4=0;c4<64;c4++) {
        float4 wv4 = wr[c4], hv4 = hh[c4];
        a += wv4.x*hv4.x; a += wv4.y*hv4.y; a += wv4.z*hv4.z; a += wv4.w*hv4.w;
      }
      a += b3[tid] + pbias[tid];
      lgp[tid] = a * 2.0f;      // /PTEMP (0.5)
    }
    __syncthreads();
    if (tid == 0) {
      float m = fmaxf(lgp[0], fmaxf(lgp[1], lgp[2]));
      float e0 = expf(lgp[0]-m), e1 = expf(lgp[1]-m), e2 = expf(lgp[2]-m);
      float Z = e0+e1+e2;
      float pw0 = e0/Z, pw1 = e1/Z, pw2 = e2/Z;
      cmb[b*4+0] = pw1;
      cmb[b*4+1] = pw0 + pw1;
      cmb[b*4+2] = pw1 + pw2;
      cmb[b*4+3] = (pw0 + pw1) + pw2;
      msum[b] = *msum_s;
    }
    return;
  }
  if (blockIdx.x >= 772) {
    unsigned i = (blockIdx.x - 772u)*256u + tid;
    uint2 rr = threefry_0_42(i, i + 0x1000000u);
    jit[i]              = norm_from_bits(rr.x);
    jit[i + 0x1000000u] = norm_from_bits(rr.y);
    return;
  }
  int idx = blockIdx.x - 4;
  int bm = idx & 31, bn = idx >> 5;
  int ty = tid >> 4, tx = tid & 15;
  v2f acc2[8][2];
  #pragma unroll
  for (int i=0;i<8;i++) { acc2[i][0] = mkv2(0.f,0.f); acc2[i][1] = mkv2(0.f,0.f); }
  for (int kt=0; kt<16; ++kt) {
    #pragma unroll
    for (int q4=0;q4<4;q4++) {
      int f = tid*4+q4; int row = f>>3; int cc = (f&7)*4;   // row 0..127
      float4 ga = *(const float4*)&x[(size_t)(bm*128+row)*DM + kt*32 + cc];
      As[cc+0][row]=ga.x; As[cc+1][row]=ga.y; As[cc+2][row]=ga.z; As[cc+3][row]=ga.w;
    }
    #pragma unroll
    for (int q4=0;q4<2;q4++) {
      int f = tid*2+q4; int row = f>>3; int cc = (f&7)*4;   // row 0..63
      float4 gb = *(const float4*)&w[(size_t)(bn*64+row)*DM + kt*32 + cc];
      Bs[cc+0][row]=gb.x; Bs[cc+1][row]=gb.y; Bs[cc+2][row]=gb.z; Bs[cc+3][row]=gb.w;
    }
    __syncthreads();
    #pragma unroll
    for (int kk=0;kk<32;kk++) {
      float4 a0 = *(const float4*)&As[kk][ty*8];
      float4 a1 = *(const float4*)&As[kk][ty*8+4];
      float4 b4 = *(const float4*)&Bs[kk][tx*4];
      float av[8] = {a0.x,a0.y,a0.z,a0.w,a1.x,a1.y,a1.z,a1.w};
      v2f b01 = mkv2(b4.x,b4.y), b23 = mkv2(b4.z,b4.w);
      #pragma unroll
      for (int i=0;i<8;i++) {
        v2f s = mkv2(av[i], av[i]);
        acc2[i][0] = __builtin_elementwise_fma(s, b01, acc2[i][0]);
        acc2[i][1] = __builtin_elementwise_fma(s, b23, acc2[i][1]);
      }
    }
    __syncthreads();
  }
  float acc[8][4];
  #pragma unroll
  for (int i=0;i<8;i++) {
    acc[i][0]=acc2[i][0].x; acc[i][1]=acc2[i][0].y;
    acc[i][2]=acc2[i][1].x; acc[i][3]=acc2[i][1].y;
  }
  int m0 = bn*64;
  int s = m0 >> 9;
  int h = (m0 >> 6) & 7;
  int b = bm >> 3;               // 8 blocks of 128 tokens per batch
  int l0 = (bm & 7) * 128;
  int d0 = tx*4;
  if (s == 0 || s == 2) {
    unsigned off = (s == 0) ? OFF_Q : OFF_V;   // row-major (L,64) for both
    #pragma unroll
    for (int i=0;i<8;i++) {
      int l = l0 + ty*8 + i;
      float4 o = {acc[i][0],acc[i][1],acc[i][2],acc[i][3]};
      *(float4*)&ws[off + ((size_t)((b*NH+h)*SEQ + l))*HD + d0] = o;
    }
  } else {
    size_t base = OFF_KT + ((size_t)((b*NH+h)*HD))*SEQ;
    #pragma unroll
    for (int j=0;j<4;j++) {
      float4 c0 = {acc[0][j], acc[1][j], acc[2][j], acc[3][j]};
      float4 c1 = {acc[4][j], acc[5][j], acc[6][j], acc[7][j]};
      size_t cb = base + (size_t)(d0+j)*SEQ + l0 + ty*8;
      *(float4*)&ws[cb]     = c0;
      *(float4*)&ws[cb + 4] = c1;
    }
  }
}

// ---------------- K3: fused scores + jitter + top-k select + softmax + PV ----------------
// r11 structure; P3 histograms now 2 bank-shifted copies selected by lane parity
// (same-bucket atomic bursts split across 2 banks; counts = copy0+copy1, integer,
// order-independent -> bit-identical selection).
template<int USEJIT>
__global__ __launch_bounds__(256, 4) void k_attn(
    const float* __restrict__ ws_q, const float* __restrict__ ws_kT, const float* __restrict__ ws_v,
    const int* __restrict__ mask, const float* __restrict__ cmb, const int* __restrict__ msum,
    const float* __restrict__ sparse_w, const float* __restrict__ sparse_b,
    const float* __restrict__ jit, float* __restrict__ ao) {
  __shared__ __align__(16) float pbuf[ROWS][SEQ];      // 32KB; aliased: hist (16.1KB, P3), red (6KB, P5 tail)
  __shared__ __align__(16) float q_s[ROWS][HD];        // 2KB
  __shared__ float mxred[4][ROWS], smred[4][ROWS];
  __shared__ unsigned pfx_s[ROWS];
  __shared__ int want_s[ROWS];
  __shared__ float mxrow[ROWS], rowsum[ROWS];
  __shared__ float cmb_s[4];

  unsigned* hist = (unsigned*)&pbuf[0][0];             // [2][HSTRIDE] (P3 only)
  float (*red)[ROWS][HD] = (float (*)[ROWS][HD])&pbuf[0][0]; // [3][ROWS][HD] (P5 tail only)

  int tid = threadIdx.x;
  int gid = blockIdx.x;
  int bh = gid >> 7;            // 0..31
  int rt = gid & 127;
  int b = bh >> 3, h = bh & 7;
  int qbase = rt * ROWS;

  // P0: stage q rows + combined values + init select state
  {
    const float* qp = ws_q + ((size_t)bh*SEQ + qbase)*HD;
    if (tid < 128) ((float4*)q_s)[tid] = ((const float4*)qp)[tid];
    if (tid < 4) cmb_s[tid] = cmb[b*4+tid];
    if (tid < ROWS) { pfx_s[tid] = 0u; want_s[tid] = WANT; }
  }
  __syncthreads();

  // P1: scores -> registers. score[c][r] for key j=tid*4+c, row r.
  float score[4][ROWS];
  {
    const float* kT = ws_kT + (size_t)bh*HD*SEQ;
    #pragma unroll
    for (int c=0;c<4;c++)
      #pragma unroll
      for (int r=0;r<ROWS;r++) score[c][r]=0.f;
    for (int d4=0; d4<16; ++d4) {
      float4 qv[ROWS];
      #pragma unroll
      for (int r=0;r<ROWS;r++) qv[r] = *(const float4*)&q_s[r][d4*4];
      float4 ka = *(const float4*)&kT[(size_t)(d4*4+0)*SEQ + tid*4];
      float4 kb = *(const float4*)&kT[(size_t)(d4*4+1)*SEQ + tid*4];
      float4 kc = *(const float4*)&kT[(size_t)(d4*4+2)*SEQ + tid*4];
      float4 kd = *(const float4*)&kT[(size_t)(d4*4+3)*SEQ + tid*4];
      #pragma unroll
      for (int r=0;r<ROWS;r++) {
        score[0][r] += qv[r].x*ka.x + qv[r].y*kb.x + qv[r].z*kc.x + qv[r].w*kd.x;
        score[1][r] += qv[r].x*ka.y + qv[r].y*kb.y + qv[r].z*kc.y + qv[r].w*kd.y;
        score[2][r] += qv[r].x*ka.z + qv[r].y*kb.z + qv[r].z*kc.z + qv[r].w*kd.z;
        score[3][r] += qv[r].x*ka.w + qv[r].y*kb.w + qv[r].z*kc.w + qv[r].w*kd.w;
      }
    }
    #pragma unroll
    for (int c=0;c<4;c++)
      #pragma unroll
      for (int r=0;r<ROWS;r++)
        score[c][r] *= 0.125f;   // * hd^-0.5
  }

  // P2: sortable(s + jitter) -> registers
  unsigned u[4][ROWS];
  {
    float sw = sparse_w[h], sb = sparse_b[h];
    #pragma unroll
    for (int r=0;r<ROWS;r++) {
      unsigned fbase = ((unsigned)bh << 20) + ((unsigned)(qbase + r) << 10);
      float jv[4];
      if (USEJIT) {
        float4 j4 = *(const float4*)&jit[fbase + (unsigned)(tid*4)];
        jv[0]=j4.x; jv[1]=j4.y; jv[2]=j4.z; jv[3]=j4.w;
      } else {
        #pragma unroll
        for (int c=0;c<4;c++) jv[c] = jitter_val(fbase + (unsigned)(tid*4+c));
      }
      #pragma unroll
      for (int c=0;c<4;c++) {
        float s = score[c][r]*sw + sb + jv[c];
        unsigned bu = __float_as_uint(s);
        u[c][r] = (bu & 0x80000000u) ? ~bu : (bu | 0x80000000u);
      }
    }
  }

  // P3: exact 716th-largest per row via 4-pass radix select; 2-copy histograms.
  {
    int r2 = tid >> 5, w = tid & 31;    // 32 threads scan per row
    unsigned* myh = hist + (tid & 1)*HSTRIDE;
    for (int pass=0; pass<4; ++pass) {
      int shift = 24 - 8*pass;
      for (int e = tid; e < 2*HSTRIDE; e += 256) hist[e] = 0u;
      __syncthreads();
      if (pass == 0) {
        #pragma unroll
        for (int r=0;r<ROWS;r++) {
          unsigned a = u[0][r] >> 24, bb = u[1][r] >> 24,
                   cc = u[2][r] >> 24, dd = u[3][r] >> 24;
          if (a == bb && a == cc && a == dd) {
            atomicAdd(&myh[r*256 + a], 4u);
          } else {
            atomicAdd(&myh[r*256 + a], 1u);
            atomicAdd(&myh[r*256 + bb], 1u);
            atomicAdd(&myh[r*256 + cc], 1u);
            atomicAdd(&myh[r*256 + dd], 1u);
          }
        }
      } else {
        unsigned hmask = 0xFFFFFFFFu << (shift+8);
        #pragma unroll
        for (int r=0;r<ROWS;r++) {
          unsigned pf = pfx_s[r];
          #pragma unroll
          for (int c=0;c<4;c++) {
            unsigned uu = u[c][r];
            if ((uu & hmask) == pf) atomicAdd(&myh[r*256 + ((uu>>shift)&255u)], 1u);
          }
        }
      }
      __syncthreads();
      unsigned cs = 0;
      #pragma unroll
      for (int k=0;k<8;k++) cs += hist[r2*256 + w*8 + k] + hist[HSTRIDE + r2*256 + w*8 + k];
      unsigned is = cs;
      #pragma unroll
      for (int off=1; off<32; off<<=1) {
        unsigned tt = __shfl_down(is, off, 32);
        if (w + off < 32) is += tt;
      }
      unsigned es = is - cs;   // count in strictly-higher chunks
      int want = want_s[r2];
      if ((int)es <= want && want < (int)(es + cs)) {
        int cacc = (int)es;
        for (int k=7;k>=0;k--) {
          unsigned hc = hist[r2*256 + w*8 + k] + hist[HSTRIDE + r2*256 + w*8 + k];
          if (want < cacc + (int)hc) {
            pfx_s[r2] |= ((unsigned)(w*8+k)) << shift;
            want_s[r2] = want - cacc;
            break;
          }
          cacc += (int)hc;
        }
      }
      __syncthreads();
    }
  }

  // pack sparse-select bits, freeing u[]
  unsigned spmask = 0u;
  {
    #pragma unroll
    for (int r=0;r<ROWS;r++) {
      unsigned Tr = pfx_s[r];
      #pragma unroll
      for (int c=0;c<4;c++)
        if (u[c][r] >= Tr) spmask |= 1u << (r*4+c);
    }
  }

  // P4: masking + block-wide softmax; p written to pbuf (float4 per row)
  {
    float c00 = cmb_s[0], c10 = cmb_s[1], c01 = cmb_s[2], c11 = cmb_s[3];
    int msum_b = msum[b];
    const int4 m4 = *(const int4*)&mask[b*SEQ + tid*4];
    int mv[4] = {m4.x, m4.y, m4.z, m4.w};
    bool okm[4];
    #pragma unroll
    for (int c=0;c<4;c++) {
      int j = tid*4 + c;
      okm[c] = (mv[c] != 0) || (msum_b == 0 && j == 0);
    }
    float lmax[ROWS];
    #pragma unroll
    for (int r=0;r<ROWS;r++) {
      int qr = qbase + r;
      float lm = -INFINITY;
      #pragma unroll
      for (int c=0;c<4;c++) {
        int j = tid*4 + c;
        bool sp = (spmask >> (r*4+c)) & 1u;
        int dj = j - qr; dj = dj < 0 ? -dj : dj;
        float comb = (dj <= 16) ? (sp ? c11 : c10) : (sp ? c01 : c00);
        float val = (comb > 0.1f && okm[c]) ? score[c][r] : -INFINITY;
        score[c][r] = val;
        lm = fmaxf(lm, val);
      }
      lmax[r] = lm;
    }
    #pragma unroll
    for (int r=0;r<ROWS;r++)
      #pragma unroll
      for (int off=32; off>=1; off>>=1)
        lmax[r] = fmaxf(lmax[r], __shfl_xor(lmax[r], off, 64));
    int wv = tid >> 6, lane = tid & 63;
    if (lane == 0) {
      #pragma unroll
      for (int r=0;r<ROWS;r++) mxred[wv][r] = lmax[r];
    }
    __syncthreads();
    if (tid < ROWS)
      mxrow[tid] = fmaxf(fmaxf(mxred[0][tid], mxred[1][tid]), fmaxf(mxred[2][tid], mxred[3][tid]));
    __syncthreads();
    float lsum[ROWS];
    #pragma unroll
    for (int r=0;r<ROWS;r++) {
      float M = mxrow[r];
      bool allm = (M == -INFINITY);
      float p0, p1, p2, p3;
      if (allm) {
        p0 = (tid == 0) ? 1.0f : 0.0f; p1 = 0.f; p2 = 0.f; p3 = 0.f;
      } else {
        p0 = __expf(score[0][r] - M);
        p1 = __expf(score[1][r] - M);
        p2 = __expf(score[2][r] - M);
        p3 = __expf(score[3][r] - M);
      }
      float4 pv = {p0,p1,p2,p3};
      *(float4*)&pbuf[r][tid*4] = pv;
      lsum[r] = p0+p1+p2+p3;
    }
    #pragma unroll
    for (int r=0;r<ROWS;r++)
      #pragma unroll
      for (int off=32; off>=1; off>>=1)
        lsum[r] += __shfl_xor(lsum[r], off, 64);
    if (lane == 0) {
      #pragma unroll
      for (int r=0;r<ROWS;r++) smred[wv][r] = lsum[r];
    }
    __syncthreads();
    if (tid < ROWS)
      rowsum[tid] = smred[0][tid] + smred[1][tid] + smred[2][tid] + smred[3][tid];
  }
  __syncthreads();

  // P5: PV with packed v2f accumulators; V natural layout (coalesced scalar loads).
  {
    int wv = tid >> 6, l = tid & 63;
    const float* vrow = ws_v + ((size_t)bh*SEQ)*HD + l;
    float acc[ROWS];
    v2f acc2[ROWS];
    #pragma unroll
    for (int r=0;r<ROWS;r++) acc2[r] = mkv2(0.f,0.f);
    int jb = wv*256;
    for (int j8=0;j8<32;j8++) {
      int j = jb + j8*8;
      float v0 = vrow[(size_t)(j+0)*HD];
      float v1 = vrow[(size_t)(j+1)*HD];
      float v2 = vrow[(size_t)(j+2)*HD];
      float v3 = vrow[(size_t)(j+3)*HD];
      float v4 = vrow[(size_t)(j+4)*HD];
      float v5 = vrow[(size_t)(j+5)*HD];
      float v6 = vrow[(size_t)(j+6)*HD];
      float v7 = vrow[(size_t)(j+7)*HD];
      v2f va01 = mkv2(v0,v1), va23 = mkv2(v2,v3);
      v2f vb01 = mkv2(v4,v5), vb23 = mkv2(v6,v7);
      #pragma unroll
      for (int r=0;r<ROWS;r++) {
        float4 pa = *(const float4*)&pbuf[r][j];
        float4 pb = *(const float4*)&pbuf[r][j+4];
        v2f t = acc2[r];
        t = __builtin_elementwise_fma(mkv2(pa.x,pa.y), va01, t);
        t = __builtin_elementwise_fma(mkv2(pa.z,pa.w), va23, t);
        t = __builtin_elementwise_fma(mkv2(pb.x,pb.y), vb01, t);
        t = __builtin_elementwise_fma(mkv2(pb.z,pb.w), vb23, t);
        acc2[r] = t;
      }
    }
    #pragma unroll
    for (int r=0;r<ROWS;r++) acc[r] = acc2[r].x + acc2[r].y;
    __syncthreads();   // all pbuf reads done before red (aliased) writes
    if (wv > 0) {
      #pragma unroll
      for (int r=0;r<ROWS;r++) red[wv-1][r][l] = acc[r];
    }
    __syncthreads();
    if (wv == 0) {
      #pragma unroll
      for (int r=0;r<ROWS;r++) {
        float tot = acc[r] + red[0][r][l] + red[1][r][l] + red[2][r][l];
        ao[((size_t)(b*SEQ + qbase + r))*DM + h*HD + l] = tot / rowsum[r];
      }
    }
  }
}

// ---------------- K4: output projection + bias (128x64 tile, packed FMA) ----------------
__global__ __launch_bounds__(256) void k_proj(const float* __restrict__ aoin, const float* __restrict__ w,
                                              const float* __restrict__ bias, float* __restrict__ out) {
  __shared__ __align__(16) float As[32][128];   // 16KB
  __shared__ __align__(16) float Bs[32][64];    // 8KB
  int tid = threadIdx.x;
  int bm = blockIdx.x, bn = blockIdx.y;
  int ty = tid >> 4, tx = tid & 15;
  v2f acc2[8][2];
  #pragma unroll
  for (int i=0;i<8;i++) { acc2[i][0] = mkv2(0.f,0.f); acc2[i][1] = mkv2(0.f,0.f); }
  for (int kt=0; kt<16; ++kt) {
    #pragma unroll
    for (int q4=0;q4<4;q4++) {
      int f = tid*4+q4; int row = f>>3; int cc = (f&7)*4;   // row 0..127
      float4 ga = *(const float4*)&aoin[(size_t)(bm*128+row)*DM + kt*32 + cc];
      As[cc+0][row]=ga.x; As[cc+1][row]=ga.y; As[cc+2][row]=ga.z; As[cc+3][row]=ga.w;
    }
    #pragma unroll
    for (int q4=0;q4<2;q4++) {
      int f = tid*2+q4; int row = f>>3; int cc = (f&7)*4;   // row 0..63
      float4 gb = *(const float4*)&w[(size_t)(bn*64+row)*DM + kt*32 + cc];
      Bs[cc+0][row]=gb.x; Bs[cc+1][row]=gb.y; Bs[cc+2][row]=gb.z; Bs[cc+3][row]=gb.w;
    }
    __syncthreads();
    #pragma unroll
    for (int kk=0;kk<32;kk++) {
      float4 a0 = *(const float4*)&As[kk][ty*8];
      float4 a1 = *(const float4*)&As[kk][ty*8+4];
      float4 b4 = *(const float4*)&Bs[kk][tx*4];
      float av[8] = {a0.x,a0.y,a0.z,a0.w,a1.x,a1.y,a1.z,a1.w};
      v2f b01 = mkv2(b4.x,b4.y), b23 = mkv2(b4.z,b4.w);
      #pragma unroll
      for (int i=0;i<8;i++) {
        v2f s = mkv2(av[i], av[i]);
        acc2[i][0] = __builtin_elementwise_fma(s, b01, acc2[i][0]);
        acc2[i][1] = __builtin_elementwise_fma(s, b23, acc2[i][1]);
      }
    }
    __syncthreads();
  }
  int o0 = bn*64 + tx*4;
  float4 bvv = *(const float4*)&bias[o0];
  #pragma unroll
  for (int i=0;i<8;i++) {
    int tok = bm*128 + ty*8 + i;
    float4 o;
    o.x = acc2[i][0].x + bvv.x; o.y = acc2[i][0].y + bvv.y;
    o.z = acc2[i][1].x + bvv.z; o.w = acc2[i][1].y + bvv.w;
    *(float4*)&out[(size_t)tok*DM + o0] = o;
  }
}

// ---------------- launch ----------------
extern "C" void kernel_launch(void* const* d_in, const int* in_sizes, int n_in,
                              void* d_out, int out_size, void* d_ws, size_t ws_size,
                              hipStream_t stream) {
  const float* x        = (const float*)d_in[0];
  const int*   mask     = (const int*)  d_in[1];
  const float* qkv_w    = (const float*)d_in[2];
  const float* proj_w   = (const float*)d_in[3];
  const float* proj_b   = (const float*)d_in[4];
  const float* ps_w1    = (const float*)d_in[5];
  const float* ps_b1    = (const float*)d_in[6];
  const float* ps_w2    = (const float*)d_in[7];
  const float* ps_b2    = (const float*)d_in[8];
  const float* ps_w3    = (const float*)d_in[9];
  const float* ps_b3    = (const float*)d_in[10];
  const float* pbias    = (const float*)d_in[11];
  const float* sparse_w = (const float*)d_in[12];
  const float* sparse_b = (const float*)d_in[13];
  float* ws  = (float*)d_ws;
  float* out = (float*)d_out;

  const bool use_jit = (ws_size >= WS_NEED_BYTES);

  k_pool<<<dim3(NB,8), 512, 0, stream>>>(x, ws + OFF_PART);
  // fused: blocks 0..3 = pattern MLP; 4..771 = qkv GEMM; 772.. = jitter precompute
  k_fused<<<use_jit ? 66308 : 772, 256, 0, stream>>>(x, qkv_w, ws, ws + OFF_JIT,
      ws + OFF_PART, mask, ps_w1, ps_b1, ps_w2, ps_b2, ps_w3, ps_b3, pbias,
      ws + OFF_CMB, (int*)(ws + OFF_MSUM));
  if (use_jit) {
    k_attn<1><<<NB*NH*(SEQ/ROWS), 256, 0, stream>>>(ws + OFF_Q, ws + OFF_KT, ws + OFF_V, mask,
                                                    ws + OFF_CMB, (const int*)(ws + OFF_MSUM),
                                                    sparse_w, sparse_b, ws + OFF_JIT, ws + OFF_AO);
  } else {
    k_attn<0><<<NB*NH*(SEQ/ROWS), 256, 0, stream>>>(ws + OFF_Q, ws + OFF_KT, ws + OFF_V, mask,
                                                    ws + OFF_CMB, (const int*)(ws + OFF_MSUM),
                                                    sparse_w, sparse_b, ws + OFF_JIT, ws + OFF_AO);
  }
  k_proj<<<dim3(32,8), 256, 0, stream>>>(ws + OFF_AO, proj_w, proj_b, out);
}